// Round 3
// baseline (1167.079 us; speedup 1.0000x reference)
//
#include <hip/hip_runtime.h>
#include <hip/hip_bf16.h>

typedef short bf16x8 __attribute__((ext_vector_type(8)));
typedef float f32x16 __attribute__((ext_vector_type(16)));
typedef int   i32x4v __attribute__((ext_vector_type(4)));
typedef unsigned u32;

#define MFMA32(a,b,c) __builtin_amdgcn_mfma_f32_32x32x16_bf16((a),(b),(c),0,0,0)

__device__ __forceinline__ u32 pkbf(float x, float y) {
  union { u32 u; __hip_bfloat16 h[2]; } t;
  t.h[0] = __float2bfloat16(x);
  t.h[1] = __float2bfloat16(y);
  return t.u;
}
__device__ __forceinline__ float bf2f(u32 lo16) {
  union { u32 u; float f; } t; t.u = lo16 << 16; return t.f;
}
__device__ __forceinline__ float silu_f(float v) { return v / (1.f + __expf(-v)); }
__device__ __forceinline__ float tanh_f(float v) {
  float e = __expf(2.f * fabsf(v));
  float t = 1.f - 2.f / (e + 1.f);
  return copysignf(t, v);
}

// Stage [128][128] f32 weight block (row k = in, col j = out) into LDS
// transposed bf16 wA[j][k] with 16B-unit XOR swizzle.
template<int NT>
__device__ __forceinline__ void stage_w128t(const float* __restrict__ W, short* wA, int tid) {
  #pragma unroll
  for (int i = 0; i < 8192 / NT; ++i) {
    int p = tid + i * NT;
    int j = p & 127;
    int k = (p >> 7) << 1;
    u32 u = pkbf(W[k * 128 + j], W[k * 128 + 128 + j]);
    int off = j * 256 + (((k >> 3) ^ (j & 15)) << 4) + ((k & 7) << 1);
    *(u32*)((char*)wA + off) = u;
  }
}
__device__ __forceinline__ bf16x8 ldsA(const short* wA, int j, int kbase) {
  int off = j * 256 + (((kbase >> 3) ^ (j & 15)) << 4);
  return __builtin_bit_cast(bf16x8, *(const i32x4v*)((const char*)wA + off));
}

__device__ __forceinline__ void zacc4(f32x16 (&acc)[4]) {
  #pragma unroll
  for (int jm = 0; jm < 4; ++jm)
    #pragma unroll
    for (int r = 0; r < 16; ++r) acc[jm][r] = 0.f;
}

// Store one jm-block (32 dims) of a row as 2x16B contiguous chunks per lane,
// after a hi-pair exchange. p0..p7 are bf16 pairs of v[0..15] in C-layout order.
__device__ __forceinline__ void row_chunks(u32 p0, u32 p1, u32 p2, u32 p3,
                                           u32 p4, u32 p5, u32 p6, u32 p7,
                                           int hi, char* rowptr, int jm) {
  u32 x0 = (u32)__shfl_xor((int)(hi ? p0 : p4), 32);
  u32 x1 = (u32)__shfl_xor((int)(hi ? p1 : p5), 32);
  u32 x2 = (u32)__shfl_xor((int)(hi ? p2 : p6), 32);
  u32 x3 = (u32)__shfl_xor((int)(hi ? p3 : p7), 32);
  i32x4v c0, c1;
  if (hi) {
    c0[0] = (int)x0; c0[1] = (int)x1; c0[2] = (int)p4; c0[3] = (int)p5;
    c1[0] = (int)x2; c1[1] = (int)x3; c1[2] = (int)p6; c1[3] = (int)p7;
  } else {
    c0[0] = (int)p0; c0[1] = (int)p1; c0[2] = (int)x0; c0[3] = (int)x1;
    c1[0] = (int)p2; c1[1] = (int)p3; c1[2] = (int)x2; c1[3] = (int)x3;
  }
  *(i32x4v*)(rowptr + jm * 64 + hi * 32)      = c0;
  *(i32x4v*)(rowptr + jm * 64 + hi * 32 + 16) = c1;
}

// C-layout -> silu(+bias) -> bf16 B-fragments for next K=128 GEMM.
__device__ __forceinline__ void trans1(f32x16 (&acc)[4], const float* bias, int hi,
                                       i32x4v (&bfr)[8]) {
  #pragma unroll
  for (int jm = 0; jm < 4; ++jm) {
    float v[16];
    #pragma unroll
    for (int r = 0; r < 16; ++r) {
      int rowloc = (r & 3) + 8 * (r >> 2) + 4 * hi;
      v[r] = silu_f(acc[jm][r] + bias[jm * 32 + rowloc]);
    }
    #pragma unroll
    for (int blk = 0; blk < 2; ++blk) {
      int r0 = blk * 8;
      u32 pa = pkbf(v[r0 + 0], v[r0 + 1]);
      u32 pb = pkbf(v[r0 + 2], v[r0 + 3]);
      u32 pc = pkbf(v[r0 + 4], v[r0 + 5]);
      u32 pd = pkbf(v[r0 + 6], v[r0 + 7]);
      u32 g1 = (u32)__shfl_xor((int)(hi ? pa : pc), 32);
      u32 g2 = (u32)__shfl_xor((int)(hi ? pb : pd), 32);
      i32x4v w;
      w[0] = hi ? (int)g1 : (int)pa;
      w[1] = hi ? (int)g2 : (int)pb;
      w[2] = hi ? (int)pc : (int)g1;
      w[3] = hi ? (int)pd : (int)g2;
      bfr[jm * 2 + blk] = w;
    }
  }
}

// Same, plus contiguous-chunk row store (sorted slot layout).
__device__ __forceinline__ void trans2s(f32x16 (&acc)[4], const float* bias, int hi,
                                        i32x4v (&bfr)[8], char* rowptr) {
  #pragma unroll
  for (int jm = 0; jm < 4; ++jm) {
    float v[16];
    #pragma unroll
    for (int r = 0; r < 16; ++r) {
      int rowloc = (r & 3) + 8 * (r >> 2) + 4 * hi;
      v[r] = silu_f(acc[jm][r] + bias[jm * 32 + rowloc]);
    }
    u32 p0 = pkbf(v[0], v[1]),  p1 = pkbf(v[2], v[3]);
    u32 p2 = pkbf(v[4], v[5]),  p3 = pkbf(v[6], v[7]);
    u32 p4 = pkbf(v[8], v[9]),  p5 = pkbf(v[10], v[11]);
    u32 p6 = pkbf(v[12], v[13]), p7 = pkbf(v[14], v[15]);
    // B-fragments for next GEMM
    {
      u32 g1 = (u32)__shfl_xor((int)(hi ? p0 : p2), 32);
      u32 g2 = (u32)__shfl_xor((int)(hi ? p1 : p3), 32);
      i32x4v w;
      w[0] = hi ? (int)g1 : (int)p0;
      w[1] = hi ? (int)g2 : (int)p1;
      w[2] = hi ? (int)p2 : (int)g1;
      w[3] = hi ? (int)p3 : (int)g2;
      bfr[jm * 2] = w;
      u32 g1b = (u32)__shfl_xor((int)(hi ? p4 : p6), 32);
      u32 g2b = (u32)__shfl_xor((int)(hi ? p5 : p7), 32);
      i32x4v w2;
      w2[0] = hi ? (int)g1b : (int)p4;
      w2[1] = hi ? (int)g2b : (int)p5;
      w2[2] = hi ? (int)p6 : (int)g1b;
      w2[3] = hi ? (int)p7 : (int)g2b;
      bfr[jm * 2 + 1] = w2;
    }
    if (rowptr) row_chunks(p0, p1, p2, p3, p4, p5, p6, p7, hi, rowptr, jm);
  }
}

// ===================== NEW PATH =====================

__global__ void kconv(const float* __restrict__ h, char* __restrict__ hbf, int total16) {
  int i = blockIdx.x * 256 + threadIdx.x;
  if (i >= total16) return;
  const float4* h4 = (const float4*)h;
  float4 a = h4[(size_t)i * 2], b = h4[(size_t)i * 2 + 1];
  i32x4v w;
  w[0] = (int)pkbf(a.x, a.y); w[1] = (int)pkbf(a.z, a.w);
  w[2] = (int)pkbf(b.x, b.y); w[3] = (int)pkbf(b.z, b.w);
  *(i32x4v*)(hbf + (size_t)i * 16) = w;
}

__global__ void khist(const int* __restrict__ src, int* __restrict__ cnt, int E) {
  int e = blockIdx.x * 256 + threadIdx.x;
  if (e < E) atomicAdd(&cnt[src[e]], 1);
}

__global__ void kscan1(const int* __restrict__ cnt, int* __restrict__ part,
                       int* __restrict__ bsums, int N) {
  __shared__ int sh[1024];
  int tid = threadIdx.x, i = blockIdx.x * 1024 + tid;
  int v = (i < N) ? cnt[i] : 0;
  sh[tid] = v; __syncthreads();
  for (int off = 1; off < 1024; off <<= 1) {
    int t = (tid >= off) ? sh[tid - off] : 0;
    __syncthreads();
    sh[tid] += t;
    __syncthreads();
  }
  if (i < N) part[i] = sh[tid] - v;
  if (tid == 1023) bsums[blockIdx.x] = sh[1023];
}

__global__ void kscan2(int* __restrict__ bsums, int nb) {
  __shared__ int sh[64];
  int tid = threadIdx.x;
  int v = (tid < nb) ? bsums[tid] : 0;
  sh[tid] = v; __syncthreads();
  for (int off = 1; off < 64; off <<= 1) {
    int t = (tid >= off) ? sh[tid - off] : 0;
    __syncthreads();
    sh[tid] += t;
    __syncthreads();
  }
  if (tid < nb) bsums[tid] = sh[tid] - v;
}

__global__ void kscan3(const int* __restrict__ bsums, int* __restrict__ part,
                       int* __restrict__ head, int N) {
  int i = blockIdx.x * 1024 + threadIdx.x;
  if (i < N) {
    int v = part[i] + bsums[blockIdx.x];
    part[i] = v;
    head[i] = v;
  }
}

__global__ void kscatter(const int* __restrict__ src, int* __restrict__ head,
                         int* __restrict__ eidx, int E) {
  int e = blockIdx.x * 256 + threadIdx.x;
  if (e < E) {
    int p = atomicAdd(&head[src[e]], 1);
    eidx[p] = e;
  }
}

// Persistent barrier-free edge kernel over SORTED slots; all 4 weight
// matrices LDS-resident; 16 waves/block (4 per SIMD).
__global__ __launch_bounds__(1024)
void kedge(const char* __restrict__ hbf, const int* __restrict__ src, const int* __restrict__ dst,
           const float* __restrict__ dist, const float* __restrict__ bpp,
           const float* __restrict__ msa, const float* __restrict__ chem,
           const float* __restrict__ rel, const float* __restrict__ cbm,
           const float* __restrict__ mW1, const float* __restrict__ mb1,
           const float* __restrict__ mW2, const float* __restrict__ mb2,
           const float* __restrict__ cW1, const float* __restrict__ cb1,
           const float* __restrict__ cW2v, const float* __restrict__ cb2,
           const int* __restrict__ eidx, char* __restrict__ m_ij,
           float* __restrict__ coef, int* __restrict__ dsts, int E)
{
  __shared__ short wA0[16384], wA1[16384], wA2[16384], wA3[16384];  // 4 x 32 KB
  __shared__ short wE[2048];
  __shared__ float sb1[128], sb2[128], scb1[128], scw2[128];
  __shared__ float scb2v[1];

  const int tid = threadIdx.x, wid = tid >> 6, lane = tid & 63;
  const int col = lane & 31, hi = lane >> 5;

  stage_w128t<1024>(mW1, wA0, tid);
  stage_w128t<1024>(mW1 + 16384, wA1, tid);
  stage_w128t<1024>(mW2, wA2, tid);
  stage_w128t<1024>(cW1, wA3, tid);
  #pragma unroll
  for (int i = 0; i < 2; ++i) {
    int p = tid + i * 1024;
    int j = p >> 4, kk = p & 15;
    float w = (kk < 6) ? mW1[(256 + kk) * 128 + j] : 0.f;
    wE[j * 16 + kk] = (short)(pkbf(w, 0.f) & 0xffffu);
  }
  if (tid < 128) {
    sb1[tid] = mb1[tid]; sb2[tid] = mb2[tid];
    scb1[tid] = cb1[tid]; scw2[tid] = cW2v[tid];
  }
  if (tid == 0) scb2v[0] = cb2[0];
  __syncthreads();

  const int T = (E + 31) / 32;
  const int stride = gridDim.x * 16;
  for (int t = blockIdx.x * 16 + wid; t < T; t += stride) {
    int p = t * 32 + col;               // sorted slot
    bool va = p < E;
    int pc_ = va ? p : E - 1;
    int e = eidx[pc_];
    int s = src[e], d = dst[e];
    float q  = dist[e];
    float f1 = bpp[e], f2 = msa[e], f3 = chem[e], f4 = rel[e], f5 = cbm[e];

    i32x4v bs[8], bd[8];
    #pragma unroll
    for (int kc = 0; kc < 8; ++kc)
      bs[kc] = *(const i32x4v*)(hbf + (size_t)s * 256 + kc * 32 + hi * 16);
    #pragma unroll
    for (int kc = 0; kc < 8; ++kc)
      bd[kc] = *(const i32x4v*)(hbf + (size_t)d * 256 + kc * 32 + hi * 16);

    f32x16 acc[4];
    zacc4(acc);
    #pragma unroll
    for (int kc = 0; kc < 8; ++kc) {
      bf16x8 b = __builtin_bit_cast(bf16x8, bs[kc]);
      #pragma unroll
      for (int jm = 0; jm < 4; ++jm)
        acc[jm] = MFMA32(ldsA(wA0, jm * 32 + col, kc * 16 + hi * 8), b, acc[jm]);
    }
    #pragma unroll
    for (int kc = 0; kc < 8; ++kc) {
      bf16x8 b = __builtin_bit_cast(bf16x8, bd[kc]);
      #pragma unroll
      for (int jm = 0; jm < 4; ++jm)
        acc[jm] = MFMA32(ldsA(wA1, jm * 32 + col, kc * 16 + hi * 8), b, acc[jm]);
    }
    {
      i32x4v ev;
      ev[0] = hi ? 0 : (int)pkbf(q * q, f1);
      ev[1] = hi ? 0 : (int)pkbf(f2, f3);
      ev[2] = hi ? 0 : (int)pkbf(f4, f5);
      ev[3] = 0;
      bf16x8 be = __builtin_bit_cast(bf16x8, ev);
      #pragma unroll
      for (int jm = 0; jm < 4; ++jm) {
        bf16x8 af = __builtin_bit_cast(bf16x8,
            *(const i32x4v*)((const char*)wE + (jm * 32 + col) * 32 + hi * 16));
        acc[jm] = MFMA32(af, be, acc[jm]);
      }
    }

    i32x4v bfr[8];
    trans1(acc, sb1, hi, bfr);

    zacc4(acc);
    #pragma unroll
    for (int kc = 0; kc < 8; ++kc) {
      bf16x8 b = __builtin_bit_cast(bf16x8, bfr[kc]);
      #pragma unroll
      for (int jm = 0; jm < 4; ++jm)
        acc[jm] = MFMA32(ldsA(wA2, jm * 32 + col, kc * 16 + hi * 8), b, acc[jm]);
    }
    // m = silu(t2+b2): store at SORTED slot p (contiguous tiles), repack for c-layer
    trans2s(acc, sb2, hi, bfr, va ? (m_ij + (size_t)p * 256) : nullptr);

    zacc4(acc);
    #pragma unroll
    for (int kc = 0; kc < 8; ++kc) {
      bf16x8 b = __builtin_bit_cast(bf16x8, bfr[kc]);
      #pragma unroll
      for (int jm = 0; jm < 4; ++jm)
        acc[jm] = MFMA32(ldsA(wA3, jm * 32 + col, kc * 16 + hi * 8), b, acc[jm]);
    }
    float part = 0.f;
    #pragma unroll
    for (int jm = 0; jm < 4; ++jm)
      #pragma unroll
      for (int r = 0; r < 16; ++r) {
        int rowloc = (r & 3) + 8 * (r >> 2) + 4 * hi;
        part += silu_f(acc[jm][r] + scb1[jm * 32 + rowloc]) * scw2[jm * 32 + rowloc];
      }
    part += __shfl_xor(part, 32);
    float cf = tanh_f(part + scb2v[0]);
    if (va && hi == 0) {
      coef[p] = cf;
      dsts[p] = d;    // dsts aliases eidx: same slot, read-before-write in this iter
    }
  }
}

// Streaming segmented sum over sorted slots: 16 threads per node, each owns
// 16 bytes (8 dims) of the row. Plus x epilogue.
__global__ __launch_bounds__(256)
void kagg(const char* __restrict__ m_ij, const int* __restrict__ row_start,
          const int* __restrict__ cnt, const float* __restrict__ coef,
          const int* __restrict__ dsts, const float* __restrict__ x,
          char* __restrict__ mibf, float* __restrict__ outX, int N)
{
  int n = blockIdx.x * 16 + (threadIdx.x >> 4);
  int t = threadIdx.x & 15;
  if (n >= N) return;
  int st = row_start[n], c = cnt[n];
  float a[8] = {0.f, 0.f, 0.f, 0.f, 0.f, 0.f, 0.f, 0.f};
  for (int k = 0; k < c; ++k) {
    i32x4v u = *(const i32x4v*)(m_ij + (size_t)(st + k) * 256 + t * 16);
    #pragma unroll
    for (int q = 0; q < 4; ++q) {
      u32 w = (u32)u[q];
      a[q * 2]     += bf2f(w & 0xffffu);
      a[q * 2 + 1] += bf2f(w >> 16);
    }
  }
  float inv = 1.f / fmaxf((float)c, 1.f);
  i32x4v o;
  #pragma unroll
  for (int q = 0; q < 4; ++q) o[q] = (int)pkbf(a[q * 2] * inv, a[q * 2 + 1] * inv);
  *(i32x4v*)(mibf + (size_t)n * 256 + t * 16) = o;
  if (t == 0) {
    float x0 = x[(size_t)n * 3], x1 = x[(size_t)n * 3 + 1], x2 = x[(size_t)n * 3 + 2];
    float dx = 0.f, dy = 0.f, dz = 0.f;
    for (int k = 0; k < c; ++k) {
      float cf = coef[st + k];
      int dn = dsts[st + k];
      dx += (x0 - x[(size_t)dn * 3])     * cf;
      dy += (x1 - x[(size_t)dn * 3 + 1]) * cf;
      dz += (x2 - x[(size_t)dn * 3 + 2]) * cf;
    }
    outX[(size_t)n * 3]     = x0 + dx * inv;
    outX[(size_t)n * 3 + 1] = x1 + dy * inv;
    outX[(size_t)n * 3 + 2] = x2 + dz * inv;
  }
}

// Node MLP layer1: t1h = silu([h | m_i] . hW1 + b1)
__global__ __launch_bounds__(512, 2)
void knode1(const char* __restrict__ hbf, const char* __restrict__ mibf,
            const float* __restrict__ hW1, const float* __restrict__ hb1,
            char* __restrict__ t1h, int N)
{
  __shared__ short wA0[16384], wA1[16384];
  __shared__ float sb1[128];
  const int tid = threadIdx.x, wid = tid >> 6, lane = tid & 63;
  const int col = lane & 31, hi = lane >> 5;
  stage_w128t<512>(hW1, wA0, tid);
  stage_w128t<512>(hW1 + 16384, wA1, tid);
  if (tid < 128) sb1[tid] = hb1[tid];
  __syncthreads();

  int T = (N + 31) / 32;
  int t = blockIdx.x * 8 + wid;
  if (t >= T) return;
  int n = t * 32 + col;
  bool va = n < N;
  int nc = va ? n : N - 1;

  i32x4v bh[8], bm[8];
  #pragma unroll
  for (int kc = 0; kc < 8; ++kc)
    bh[kc] = *(const i32x4v*)(hbf + (size_t)nc * 256 + kc * 32 + hi * 16);
  #pragma unroll
  for (int kc = 0; kc < 8; ++kc)
    bm[kc] = *(const i32x4v*)(mibf + (size_t)nc * 256 + kc * 32 + hi * 16);

  f32x16 acc[4];
  zacc4(acc);
  #pragma unroll
  for (int kc = 0; kc < 8; ++kc) {
    bf16x8 b = __builtin_bit_cast(bf16x8, bh[kc]);
    #pragma unroll
    for (int jm = 0; jm < 4; ++jm)
      acc[jm] = MFMA32(ldsA(wA0, jm * 32 + col, kc * 16 + hi * 8), b, acc[jm]);
  }
  #pragma unroll
  for (int kc = 0; kc < 8; ++kc) {
    bf16x8 b = __builtin_bit_cast(bf16x8, bm[kc]);
    #pragma unroll
    for (int jm = 0; jm < 4; ++jm)
      acc[jm] = MFMA32(ldsA(wA1, jm * 32 + col, kc * 16 + hi * 8), b, acc[jm]);
  }
  #pragma unroll
  for (int jm = 0; jm < 4; ++jm) {
    float v[16];
    #pragma unroll
    for (int r = 0; r < 16; ++r) {
      int rowloc = (r & 3) + 8 * (r >> 2) + 4 * hi;
      v[r] = silu_f(acc[jm][r] + sb1[jm * 32 + rowloc]);
    }
    u32 p0 = pkbf(v[0], v[1]),  p1 = pkbf(v[2], v[3]);
    u32 p2 = pkbf(v[4], v[5]),  p3 = pkbf(v[6], v[7]);
    u32 p4 = pkbf(v[8], v[9]),  p5 = pkbf(v[10], v[11]);
    u32 p6 = pkbf(v[12], v[13]), p7 = pkbf(v[14], v[15]);
    if (va) row_chunks(p0, p1, p2, p3, p4, p5, p6, p7, hi, t1h + (size_t)n * 256, jm);
  }
}

// Node MLP layer2 + residual: h_out = h + t1h . hW2 + b2
__global__ __launch_bounds__(512, 2)
void knode2(const char* __restrict__ t1h, const float* __restrict__ hW2,
            const float* __restrict__ hb2, const float* __restrict__ h,
            float* __restrict__ outH, int N)
{
  __shared__ short wA0[16384];
  __shared__ float sb2[128];
  const int tid = threadIdx.x, wid = tid >> 6, lane = tid & 63;
  const int col = lane & 31, hi = lane >> 5;
  stage_w128t<512>(hW2, wA0, tid);
  if (tid < 128) sb2[tid] = hb2[tid];
  __syncthreads();

  int T = (N + 31) / 32;
  int t = blockIdx.x * 8 + wid;
  if (t >= T) return;
  int n = t * 32 + col;
  bool va = n < N;
  int nc = va ? n : N - 1;

  i32x4v bt[8];
  #pragma unroll
  for (int kc = 0; kc < 8; ++kc)
    bt[kc] = *(const i32x4v*)(t1h + (size_t)nc * 256 + kc * 32 + hi * 16);

  f32x16 acc[4];
  zacc4(acc);
  #pragma unroll
  for (int kc = 0; kc < 8; ++kc) {
    bf16x8 b = __builtin_bit_cast(bf16x8, bt[kc]);
    #pragma unroll
    for (int jm = 0; jm < 4; ++jm)
      acc[jm] = MFMA32(ldsA(wA0, jm * 32 + col, kc * 16 + hi * 8), b, acc[jm]);
  }
  const float4* h4 = (const float4*)h;
  #pragma unroll
  for (int jm = 0; jm < 4; ++jm)
    #pragma unroll
    for (int rq = 0; rq < 4; ++rq) {
      int j0 = jm * 32 + rq * 8 + hi * 4;
      float4 hv = h4[(size_t)nc * 32 + (j0 >> 2)];
      float4 o;
      o.x = hv.x + acc[jm][rq * 4 + 0] + sb2[j0 + 0];
      o.y = hv.y + acc[jm][rq * 4 + 1] + sb2[j0 + 1];
      o.z = hv.z + acc[jm][rq * 4 + 2] + sb2[j0 + 2];
      o.w = hv.w + acc[jm][rq * 4 + 3] + sb2[j0 + 3];
      if (va) ((float4*)outH)[(size_t)nc * 32 + (j0 >> 2)] = o;
    }
}

// ===================== FALLBACK (round-1 proven path) =====================

__device__ __forceinline__ bf16x8 pack8(float4 a, float4 b) {
  i32x4v w;
  w[0] = (int)pkbf(a.x, a.y); w[1] = (int)pkbf(a.z, a.w);
  w[2] = (int)pkbf(b.x, b.y); w[3] = (int)pkbf(b.z, b.w);
  return __builtin_bit_cast(bf16x8, w);
}
__device__ __forceinline__ void zero_acc(f32x16 (&acc)[4][2]) {
  #pragma unroll
  for (int jm = 0; jm < 4; ++jm)
    #pragma unroll
    for (int et = 0; et < 2; ++et)
      #pragma unroll
      for (int r = 0; r < 16; ++r) acc[jm][et][r] = 0.f;
}
__device__ __forceinline__ void gemm_gather(const short* wA, const float4* __restrict__ base,
                                            int r0, int r1, f32x16 (&acc)[4][2], int col, int hi) {
  #pragma unroll
  for (int kc = 0; kc < 8; ++kc) {
    float4 p00 = base[(size_t)r0 * 32 + kc * 4 + hi * 2];
    float4 p01 = base[(size_t)r0 * 32 + kc * 4 + hi * 2 + 1];
    float4 p10 = base[(size_t)r1 * 32 + kc * 4 + hi * 2];
    float4 p11 = base[(size_t)r1 * 32 + kc * 4 + hi * 2 + 1];
    bf16x8 b0 = pack8(p00, p01);
    bf16x8 b1 = pack8(p10, p11);
    #pragma unroll
    for (int jm = 0; jm < 4; ++jm) {
      bf16x8 af = ldsA(wA, jm * 32 + col, kc * 16 + hi * 8);
      acc[jm][0] = MFMA32(af, b0, acc[jm][0]);
      acc[jm][1] = MFMA32(af, b1, acc[jm][1]);
    }
  }
}
__device__ __forceinline__ void gemm_gather_scaled(const short* wA, const float4* __restrict__ base,
                                                   int r0, int r1, float sc0, float sc1,
                                                   f32x16 (&acc)[4][2], int col, int hi) {
  #pragma unroll
  for (int kc = 0; kc < 8; ++kc) {
    float4 p00 = base[(size_t)r0 * 32 + kc * 4 + hi * 2];
    float4 p01 = base[(size_t)r0 * 32 + kc * 4 + hi * 2 + 1];
    float4 p10 = base[(size_t)r1 * 32 + kc * 4 + hi * 2];
    float4 p11 = base[(size_t)r1 * 32 + kc * 4 + hi * 2 + 1];
    p00.x *= sc0; p00.y *= sc0; p00.z *= sc0; p00.w *= sc0;
    p01.x *= sc0; p01.y *= sc0; p01.z *= sc0; p01.w *= sc0;
    p10.x *= sc1; p10.y *= sc1; p10.z *= sc1; p10.w *= sc1;
    p11.x *= sc1; p11.y *= sc1; p11.z *= sc1; p11.w *= sc1;
    bf16x8 b0 = pack8(p00, p01);
    bf16x8 b1 = pack8(p10, p11);
    #pragma unroll
    for (int jm = 0; jm < 4; ++jm) {
      bf16x8 af = ldsA(wA, jm * 32 + col, kc * 16 + hi * 8);
      acc[jm][0] = MFMA32(af, b0, acc[jm][0]);
      acc[jm][1] = MFMA32(af, b1, acc[jm][1]);
    }
  }
}
__device__ __forceinline__ void gemm_regB(const short* wA, i32x4v (&bfr)[2][8],
                                          f32x16 (&acc)[4][2], int col, int hi) {
  #pragma unroll
  for (int kc = 0; kc < 8; ++kc) {
    bf16x8 b0 = __builtin_bit_cast(bf16x8, bfr[0][kc]);
    bf16x8 b1 = __builtin_bit_cast(bf16x8, bfr[1][kc]);
    #pragma unroll
    for (int jm = 0; jm < 4; ++jm) {
      bf16x8 af = ldsA(wA, jm * 32 + col, kc * 16 + hi * 8);
      acc[jm][0] = MFMA32(af, b0, acc[jm][0]);
      acc[jm][1] = MFMA32(af, b1, acc[jm][1]);
    }
  }
}
template<bool ATOMIC>
__device__ __forceinline__ void transition_t(f32x16 (&acc)[4][2], const float* __restrict__ bias,
                                             i32x4v (&bfr)[2][8], int hi,
                                             float* __restrict__ m_sum,
                                             int s0, int s1, bool va0, bool va1) {
  #pragma unroll
  for (int jm = 0; jm < 4; ++jm) {
    #pragma unroll
    for (int et = 0; et < 2; ++et) {
      float v[16];
      #pragma unroll
      for (int r = 0; r < 16; ++r) {
        int rowloc = (r & 3) + 8 * (r >> 2) + 4 * hi;
        v[r] = silu_f(acc[jm][et][r] + bias[jm * 32 + rowloc]);
        if (ATOMIC) {
          int  sn = et ? s1 : s0;
          bool vv = et ? va1 : va0;
          if (vv) unsafeAtomicAdd(&m_sum[(size_t)sn * 128 + jm * 32 + rowloc], v[r]);
        }
      }
      #pragma unroll
      for (int blk = 0; blk < 2; ++blk) {
        int r0 = blk * 8;
        u32 pa = pkbf(v[r0 + 0], v[r0 + 1]);
        u32 pb = pkbf(v[r0 + 2], v[r0 + 3]);
        u32 pc = pkbf(v[r0 + 4], v[r0 + 5]);
        u32 pd = pkbf(v[r0 + 6], v[r0 + 7]);
        u32 g1 = (u32)__shfl_xor((int)(hi ? pa : pc), 32);
        u32 g2 = (u32)__shfl_xor((int)(hi ? pb : pd), 32);
        i32x4v w;
        w[0] = hi ? (int)g1 : (int)pa;
        w[1] = hi ? (int)g2 : (int)pb;
        w[2] = hi ? (int)pc : (int)g1;
        w[3] = hi ? (int)pd : (int)g2;
        bfr[et][jm * 2 + blk] = w;
      }
    }
  }
}

__global__ __launch_bounds__(256, 2)
void egnn_edge(const float* __restrict__ h, const float* __restrict__ x,
               const int* __restrict__ src, const int* __restrict__ dst,
               const float* __restrict__ dist, const float* __restrict__ bpp,
               const float* __restrict__ msa, const float* __restrict__ chem,
               const float* __restrict__ rel, const float* __restrict__ cbm,
               const float* __restrict__ mW1, const float* __restrict__ mb1,
               const float* __restrict__ mW2, const float* __restrict__ mb2,
               const float* __restrict__ cW1, const float* __restrict__ cb1,
               const float* __restrict__ cW2v, const float* __restrict__ cb2,
               float* __restrict__ m_sum, float* __restrict__ cnt,
               float* __restrict__ dsum, int N, int E)
{
  __shared__ short wA[128 * 128];
  __shared__ short wE[128 * 16];
  __shared__ float sb1[128], sb2[128], scb1[128], scw2[128];
  __shared__ float scb2[1];

  const int tid  = threadIdx.x;
  const int wid  = tid >> 6;
  const int lane = tid & 63;
  const int col  = lane & 31;
  const int hi   = lane >> 5;

  stage_w128t<256>(mW1, wA, tid);
  #pragma unroll
  for (int i = 0; i < 8; ++i) {
    int p = tid + i * 256;
    int j = p >> 4;
    int kk = p & 15;
    float w = (kk < 6) ? mW1[(256 + kk) * 128 + j] : 0.f;
    wE[j * 16 + kk] = (short)(pkbf(w, 0.f) & 0xffffu);
  }
  if (tid < 128) {
    sb1[tid]  = mb1[tid];
    sb2[tid]  = mb2[tid];
    scb1[tid] = cb1[tid];
    scw2[tid] = cW2v[tid];
  }
  if (tid == 0) scb2[0] = cb2[0];

  int eb = blockIdx.x * 256 + wid * 64;
  int e0 = eb + col, e1 = eb + 32 + col;
  bool va0 = e0 < E, va1 = e1 < E;
  int ec0 = va0 ? e0 : E - 1, ec1 = va1 ? e1 : E - 1;
  int s0e = src[ec0], s1e = src[ec1];
  int d0e = dst[ec0], d1e = dst[ec1];

  f32x16 acc[4][2];
  zero_acc(acc);
  const float4* h4 = (const float4*)h;

  __syncthreads();
  gemm_gather(wA, h4, s0e, s1e, acc, col, hi);
  __syncthreads();
  stage_w128t<256>(mW1 + 128 * 128, wA, tid);
  __syncthreads();
  gemm_gather(wA, h4, d0e, d1e, acc, col, hi);

  {
    float q0 = dist[ec0], q1 = dist[ec1];
    i32x4v e0v, e1v;
    e0v[0] = (int)pkbf(q0 * q0, bpp[ec0]);
    e0v[1] = (int)pkbf(msa[ec0], chem[ec0]);
    e0v[2] = (int)pkbf(rel[ec0], cbm[ec0]);
    e0v[3] = 0;
    e1v[0] = (int)pkbf(q1 * q1, bpp[ec1]);
    e1v[1] = (int)pkbf(msa[ec1], chem[ec1]);
    e1v[2] = (int)pkbf(rel[ec1], cbm[ec1]);
    e1v[3] = 0;
    if (hi) { e0v[0] = e0v[1] = e0v[2] = 0; e1v[0] = e1v[1] = e1v[2] = 0; }
    bf16x8 be0 = __builtin_bit_cast(bf16x8, e0v);
    bf16x8 be1 = __builtin_bit_cast(bf16x8, e1v);
    #pragma unroll
    for (int jm = 0; jm < 4; ++jm) {
      bf16x8 af = __builtin_bit_cast(bf16x8,
          *(const i32x4v*)((const char*)wE + (jm * 32 + col) * 32 + hi * 16));
      acc[jm][0] = MFMA32(af, be0, acc[jm][0]);
      acc[jm][1] = MFMA32(af, be1, acc[jm][1]);
    }
  }

  i32x4v bfr[2][8];
  transition_t<false>(acc, sb1, bfr, hi, nullptr, 0, 0, false, false);

  __syncthreads();
  stage_w128t<256>(mW2, wA, tid);
  __syncthreads();
  zero_acc(acc);
  gemm_regB(wA, bfr, acc, col, hi);

  transition_t<true>(acc, sb2, bfr, hi, m_sum, s0e, s1e, va0, va1);

  __syncthreads();
  stage_w128t<256>(cW1, wA, tid);
  __syncthreads();
  zero_acc(acc);
  gemm_regB(wA, bfr, acc, col, hi);

  float part0 = 0.f, part1 = 0.f;
  #pragma unroll
  for (int jm = 0; jm < 4; ++jm) {
    #pragma unroll
    for (int r = 0; r < 16; ++r) {
      int rowloc = (r & 3) + 8 * (r >> 2) + 4 * hi;
      float wv = scw2[jm * 32 + rowloc];
      float bb = scb1[jm * 32 + rowloc];
      part0 += silu_f(acc[jm][0][r] + bb) * wv;
      part1 += silu_f(acc[jm][1][r] + bb) * wv;
    }
  }
  part0 += __shfl_xor(part0, 32);
  part1 += __shfl_xor(part1, 32);
  float cb2v = scb2[0];
  float coef0 = tanh_f(part0 + cb2v);
  float coef1 = tanh_f(part1 + cb2v);

  if (hi == 0) {
    if (va0) {
      #pragma unroll
      for (int cc = 0; cc < 3; ++cc) {
        float df = x[(size_t)s0e * 3 + cc] - x[(size_t)d0e * 3 + cc];
        unsafeAtomicAdd(&dsum[(size_t)s0e * 3 + cc], df * coef0);
      }
      unsafeAtomicAdd(&cnt[s0e], 1.f);
    }
    if (va1) {
      #pragma unroll
      for (int cc = 0; cc < 3; ++cc) {
        float df = x[(size_t)s1e * 3 + cc] - x[(size_t)d1e * 3 + cc];
        unsafeAtomicAdd(&dsum[(size_t)s1e * 3 + cc], df * coef1);
      }
      unsafeAtomicAdd(&cnt[s1e], 1.f);
    }
  }
}

__global__ __launch_bounds__(256, 2)
void egnn_node(const float* __restrict__ h, const float* __restrict__ x,
               const float* __restrict__ hW1, const float* __restrict__ hb1,
               const float* __restrict__ hW2, const float* __restrict__ hb2,
               const float* __restrict__ m_sum, const float* __restrict__ cnt,
               const float* __restrict__ dsum, float* __restrict__ out, int N)
{
  __shared__ short wA[128 * 128];
  __shared__ float s_b1[128], s_b2[128];

  const int tid  = threadIdx.x;
  const int wid  = tid >> 6;
  const int lane = tid & 63;
  const int col  = lane & 31;
  const int hi   = lane >> 5;
  const int nb   = blockIdx.x * 256;

  float* outH = out;
  float* outX = out + (size_t)N * 128;

  #pragma unroll
  for (int i = 0; i < 3; ++i) {
    int t = tid + i * 256;
    int n = nb + t / 3, c = t % 3;
    if (n < N) {
      float den = fmaxf(cnt[n], 1.f);
      outX[(size_t)n * 3 + c] = x[(size_t)n * 3 + c] + dsum[(size_t)n * 3 + c] / den;
    }
  }

  stage_w128t<256>(hW1, wA, tid);
  if (tid < 128) { s_b1[tid] = hb1[tid]; s_b2[tid] = hb2[tid]; }

  int n0 = nb + wid * 64 + col, n1 = nb + wid * 64 + 32 + col;
  bool va0 = n0 < N, va1 = n1 < N;
  int nc0 = va0 ? n0 : N - 1, nc1 = va1 ? n1 : N - 1;
  float inv0 = 1.f / fmaxf(cnt[nc0], 1.f);
  float inv1 = 1.f / fmaxf(cnt[nc1], 1.f);

  f32x16 acc[4][2];
  zero_acc(acc);
  const float4* h4 = (const float4*)h;
  const float4* m4 = (const float4*)m_sum;

  __syncthreads();
  gemm_gather(wA, h4, nc0, nc1, acc, col, hi);
  __syncthreads();
  stage_w128t<256>(hW1 + 128 * 128, wA, tid);
  __syncthreads();
  gemm_gather_scaled(wA, m4, nc0, nc1, inv0, inv1, acc, col, hi);

  i32x4v bfr[2][8];
  transition_t<false>(acc, s_b1, bfr, hi, nullptr, 0, 0, false, false);

  __syncthreads();
  stage_w128t<256>(hW2, wA, tid);
  __syncthreads();
  zero_acc(acc);
  gemm_regB(wA, bfr, acc, col, hi);

  #pragma unroll
  for (int jm = 0; jm < 4; ++jm) {
    #pragma unroll
    for (int et = 0; et < 2; ++et) {
      int  nn = et ? nc1 : nc0;
      bool vv = et ? va1 : va0;
      #pragma unroll
      for (int rq = 0; rq < 4; ++rq) {
        int j0 = jm * 32 + rq * 8 + hi * 4;
        float4 hv = h4[(size_t)nn * 32 + (j0 >> 2)];
        float4 o;
        o.x = hv.x + acc[jm][et][rq * 4 + 0] + s_b2[j0 + 0];
        o.y = hv.y + acc[jm][et][rq * 4 + 1] + s_b2[j0 + 1];
        o.z = hv.z + acc[jm][et][rq * 4 + 2] + s_b2[j0 + 2];
        o.w = hv.w + acc[jm][et][rq * 4 + 3] + s_b2[j0 + 3];
        if (vv) ((float4*)outH)[(size_t)nn * 32 + (j0 >> 2)] = o;
      }
    }
  }
}

// ===================== LAUNCH =====================

extern "C" void kernel_launch(void* const* d_in, const int* in_sizes, int n_in,
                              void* d_out, int out_size, void* d_ws, size_t ws_size,
                              hipStream_t stream) {
  const float* h    = (const float*)d_in[0];
  const float* x    = (const float*)d_in[1];
  const int*   src  = (const int*)d_in[2];
  const int*   dst  = (const int*)d_in[3];
  const float* dist = (const float*)d_in[4];
  const float* bpp  = (const float*)d_in[5];
  const float* msa  = (const float*)d_in[6];
  const float* chem = (const float*)d_in[7];
  const float* rel  = (const float*)d_in[8];
  const float* cbm  = (const float*)d_in[9];
  const float* mW1  = (const float*)d_in[10];
  const float* mb1  = (const float*)d_in[11];
  const float* mW2  = (const float*)d_in[12];
  const float* mb2  = (const float*)d_in[13];
  const float* hW1  = (const float*)d_in[14];
  const float* hb1  = (const float*)d_in[15];
  const float* hW2  = (const float*)d_in[16];
  const float* hb2  = (const float*)d_in[17];
  const float* cW1  = (const float*)d_in[18];
  const float* cb1  = (const float*)d_in[19];
  const float* cW2  = (const float*)d_in[20];
  const float* cb2  = (const float*)d_in[21];

  int N = in_sizes[0] / 128;
  int E = in_sizes[2];

  size_t off = 0;
  auto A = [&](size_t b) { size_t o = off; off += (b + 255) & ~(size_t)255; return o; };
  size_t o_cnt  = A((size_t)N * 4);
  size_t o_rs   = A((size_t)N * 4);
  size_t o_head = A((size_t)N * 4);
  size_t o_eidx = A((size_t)E * 4);
  size_t o_coef = A((size_t)E * 4);
  size_t o_bs   = A(1024);
  size_t o_hbf  = A((size_t)N * 256);
  size_t o_mibf = A((size_t)N * 256);
  size_t o_mij  = A((size_t)E * 256);

  if (off <= ws_size) {
    char* W = (char*)d_ws;
    int*   cnt32 = (int*)(W + o_cnt);
    int*   rs    = (int*)(W + o_rs);
    int*   head  = (int*)(W + o_head);
    int*   eidx  = (int*)(W + o_eidx);
    float* coef  = (float*)(W + o_coef);
    int*   bsums = (int*)(W + o_bs);
    char*  hbf   = W + o_hbf;
    char*  mibf  = W + o_mibf;
    char*  mij   = W + o_mij;
    char*  t1h   = W + o_mij;   // alias: m_ij consumed by kagg before knode1 writes
    int*   dsts  = eidx;        // alias: eidx[p] read-then-overwritten per slot in kedge

    hipMemsetAsync(cnt32, 0, (size_t)N * 4, stream);
    kconv<<<(N * 16 + 255) / 256, 256, 0, stream>>>(h, hbf, N * 16);
    khist<<<(E + 255) / 256, 256, 0, stream>>>(src, cnt32, E);
    int nb = (N + 1023) / 1024;
    kscan1<<<nb, 1024, 0, stream>>>(cnt32, rs, bsums, N);
    kscan2<<<1, 64, 0, stream>>>(bsums, nb);
    kscan3<<<nb, 1024, 0, stream>>>(bsums, rs, head, N);
    kscatter<<<(E + 255) / 256, 256, 0, stream>>>(src, head, eidx, E);
    kedge<<<256, 1024, 0, stream>>>(hbf, src, dst, dist, bpp, msa, chem, rel, cbm,
                                    mW1, mb1, mW2, mb2, cW1, cb1, cW2, cb2,
                                    eidx, mij, coef, dsts, E);
    kagg<<<(N + 15) / 16, 256, 0, stream>>>(mij, rs, cnt32, coef, dsts, x,
                                            mibf, (float*)d_out + (size_t)N * 128, N);
    int tb = ((N + 31) / 32 + 7) / 8;
    knode1<<<tb, 512, 0, stream>>>(hbf, mibf, hW1, hb1, t1h, N);
    knode2<<<tb, 512, 0, stream>>>(t1h, hW2, hb2, h, (float*)d_out, N);
  } else {
    // fallback: round-1 proven atomic path
    float* m_sum = (float*)d_ws;
    float* cntf  = m_sum + (size_t)N * 128;
    float* dsum  = cntf + N;
    hipMemsetAsync(d_ws, 0, (size_t)N * 132 * sizeof(float), stream);
    int eblocks = (E + 255) / 256;
    egnn_edge<<<eblocks, 256, 0, stream>>>(h, x, src, dst, dist, bpp, msa, chem, rel, cbm,
                                           mW1, mb1, mW2, mb2, cW1, cb1, cW2, cb2,
                                           m_sum, cntf, dsum, N, E);
    int nblocks = (N + 255) / 256;
    egnn_node<<<nblocks, 256, 0, stream>>>(h, x, hW1, hb1, hW2, hb2,
                                           m_sum, cntf, dsum, (float*)d_out, N);
  }
}

// Round 4
// 1079.768 us; speedup vs baseline: 1.0809x; 1.0809x over previous
//
#include <hip/hip_runtime.h>
#include <hip/hip_bf16.h>

typedef short bf16x8 __attribute__((ext_vector_type(8)));
typedef float f32x16 __attribute__((ext_vector_type(16)));
typedef int   i32x4v __attribute__((ext_vector_type(4)));
typedef unsigned u32;

#define MFMA32(a,b,c) __builtin_amdgcn_mfma_f32_32x32x16_bf16((a),(b),(c),0,0,0)

__device__ __forceinline__ u32 pkbf(float x, float y) {
  union { u32 u; __hip_bfloat16 h[2]; } t;
  t.h[0] = __float2bfloat16(x);
  t.h[1] = __float2bfloat16(y);
  return t.u;
}
__device__ __forceinline__ float bf2f(u32 lo16) {
  union { u32 u; float f; } t; t.u = lo16 << 16; return t.f;
}
__device__ __forceinline__ float silu_f(float v) { return v / (1.f + __expf(-v)); }
__device__ __forceinline__ float tanh_f(float v) {
  float e = __expf(2.f * fabsf(v));
  float t = 1.f - 2.f / (e + 1.f);
  return copysignf(t, v);
}

// Stage [128][128] f32 weight block (row k = in, col j = out) into LDS
// transposed bf16 wA[j][k] with 16B-unit XOR swizzle.
template<int NT>
__device__ __forceinline__ void stage_w128t(const float* __restrict__ W, short* wA, int tid) {
  for (int p = tid; p < 8192; p += NT) {
    int j = p & 127;
    int k = (p >> 7) << 1;
    u32 u = pkbf(W[k * 128 + j], W[k * 128 + 128 + j]);
    int off = j * 256 + (((k >> 3) ^ (j & 15)) << 4) + ((k & 7) << 1);
    *(u32*)((char*)wA + off) = u;
  }
}
__device__ __forceinline__ bf16x8 ldsA(const short* wA, int j, int kbase) {
  int off = j * 256 + (((kbase >> 3) ^ (j & 15)) << 4);
  return __builtin_bit_cast(bf16x8, *(const i32x4v*)((const char*)wA + off));
}

__device__ __forceinline__ void zacc4(f32x16 (&acc)[4]) {
  #pragma unroll
  for (int jm = 0; jm < 4; ++jm)
    #pragma unroll
    for (int r = 0; r < 16; ++r) acc[jm][r] = 0.f;
}

// Store one jm-block (32 dims) of a row as 2x16B contiguous chunks per lane,
// after a hi-pair exchange. p0..p7 are bf16 pairs of v[0..15] in C-layout order.
__device__ __forceinline__ void row_chunks(u32 p0, u32 p1, u32 p2, u32 p3,
                                           u32 p4, u32 p5, u32 p6, u32 p7,
                                           int hi, char* rowptr, int jm) {
  u32 x0 = (u32)__shfl_xor((int)(hi ? p0 : p4), 32);
  u32 x1 = (u32)__shfl_xor((int)(hi ? p1 : p5), 32);
  u32 x2 = (u32)__shfl_xor((int)(hi ? p2 : p6), 32);
  u32 x3 = (u32)__shfl_xor((int)(hi ? p3 : p7), 32);
  i32x4v c0, c1;
  if (hi) {
    c0[0] = (int)x0; c0[1] = (int)x1; c0[2] = (int)p4; c0[3] = (int)p5;
    c1[0] = (int)x2; c1[1] = (int)x3; c1[2] = (int)p6; c1[3] = (int)p7;
  } else {
    c0[0] = (int)p0; c0[1] = (int)p1; c0[2] = (int)x0; c0[3] = (int)x1;
    c1[0] = (int)p2; c1[1] = (int)p3; c1[2] = (int)x2; c1[3] = (int)x3;
  }
  *(i32x4v*)(rowptr + jm * 64 + hi * 32)      = c0;
  *(i32x4v*)(rowptr + jm * 64 + hi * 32 + 16) = c1;
}

// C-layout -> silu(+bias) -> bf16 B-fragments for next K=128 GEMM.
__device__ __forceinline__ void trans1(f32x16 (&acc)[4], const float* bias, int hi,
                                       i32x4v (&bfr)[8]) {
  #pragma unroll
  for (int jm = 0; jm < 4; ++jm) {
    float v[16];
    #pragma unroll
    for (int r = 0; r < 16; ++r) {
      int rowloc = (r & 3) + 8 * (r >> 2) + 4 * hi;
      v[r] = silu_f(acc[jm][r] + bias[jm * 32 + rowloc]);
    }
    #pragma unroll
    for (int blk = 0; blk < 2; ++blk) {
      int r0 = blk * 8;
      u32 pa = pkbf(v[r0 + 0], v[r0 + 1]);
      u32 pb = pkbf(v[r0 + 2], v[r0 + 3]);
      u32 pc = pkbf(v[r0 + 4], v[r0 + 5]);
      u32 pd = pkbf(v[r0 + 6], v[r0 + 7]);
      u32 g1 = (u32)__shfl_xor((int)(hi ? pa : pc), 32);
      u32 g2 = (u32)__shfl_xor((int)(hi ? pb : pd), 32);
      i32x4v w;
      w[0] = hi ? (int)g1 : (int)pa;
      w[1] = hi ? (int)g2 : (int)pb;
      w[2] = hi ? (int)pc : (int)g1;
      w[3] = hi ? (int)pd : (int)g2;
      bfr[jm * 2 + blk] = w;
    }
  }
}

// Same, plus contiguous-chunk row store (sorted slot layout).
__device__ __forceinline__ void trans2s(f32x16 (&acc)[4], const float* bias, int hi,
                                        i32x4v (&bfr)[8], char* rowptr) {
  #pragma unroll
  for (int jm = 0; jm < 4; ++jm) {
    float v[16];
    #pragma unroll
    for (int r = 0; r < 16; ++r) {
      int rowloc = (r & 3) + 8 * (r >> 2) + 4 * hi;
      v[r] = silu_f(acc[jm][r] + bias[jm * 32 + rowloc]);
    }
    u32 p0 = pkbf(v[0], v[1]),  p1 = pkbf(v[2], v[3]);
    u32 p2 = pkbf(v[4], v[5]),  p3 = pkbf(v[6], v[7]);
    u32 p4 = pkbf(v[8], v[9]),  p5 = pkbf(v[10], v[11]);
    u32 p6 = pkbf(v[12], v[13]), p7 = pkbf(v[14], v[15]);
    {
      u32 g1 = (u32)__shfl_xor((int)(hi ? p0 : p2), 32);
      u32 g2 = (u32)__shfl_xor((int)(hi ? p1 : p3), 32);
      i32x4v w;
      w[0] = hi ? (int)g1 : (int)p0;
      w[1] = hi ? (int)g2 : (int)p1;
      w[2] = hi ? (int)p2 : (int)g1;
      w[3] = hi ? (int)p3 : (int)g2;
      bfr[jm * 2] = w;
      u32 g1b = (u32)__shfl_xor((int)(hi ? p4 : p6), 32);
      u32 g2b = (u32)__shfl_xor((int)(hi ? p5 : p7), 32);
      i32x4v w2;
      w2[0] = hi ? (int)g1b : (int)p4;
      w2[1] = hi ? (int)g2b : (int)p5;
      w2[2] = hi ? (int)p6 : (int)g1b;
      w2[3] = hi ? (int)p7 : (int)g2b;
      bfr[jm * 2 + 1] = w2;
    }
    if (rowptr) row_chunks(p0, p1, p2, p3, p4, p5, p6, p7, hi, rowptr, jm);
  }
}

// ===================== NEW PATH =====================

__global__ void kconv(const float* __restrict__ h, char* __restrict__ hbf, int total16) {
  int i = blockIdx.x * 256 + threadIdx.x;
  if (i >= total16) return;
  const float4* h4 = (const float4*)h;
  float4 a = h4[(size_t)i * 2], b = h4[(size_t)i * 2 + 1];
  i32x4v w;
  w[0] = (int)pkbf(a.x, a.y); w[1] = (int)pkbf(a.z, a.w);
  w[2] = (int)pkbf(b.x, b.y); w[3] = (int)pkbf(b.z, b.w);
  *(i32x4v*)(hbf + (size_t)i * 16) = w;
}

__global__ void khist(const int* __restrict__ src, int* __restrict__ cnt, int E) {
  int e = blockIdx.x * 256 + threadIdx.x;
  if (e < E) atomicAdd(&cnt[src[e]], 1);
}

__global__ void kscan1(const int* __restrict__ cnt, int* __restrict__ part,
                       int* __restrict__ bsums, int N) {
  __shared__ int sh[1024];
  int tid = threadIdx.x, i = blockIdx.x * 1024 + tid;
  int v = (i < N) ? cnt[i] : 0;
  sh[tid] = v; __syncthreads();
  for (int off = 1; off < 1024; off <<= 1) {
    int t = (tid >= off) ? sh[tid - off] : 0;
    __syncthreads();
    sh[tid] += t;
    __syncthreads();
  }
  if (i < N) part[i] = sh[tid] - v;
  if (tid == 1023) bsums[blockIdx.x] = sh[1023];
}

__global__ void kscan2(int* __restrict__ bsums, int nb) {
  __shared__ int sh[64];
  int tid = threadIdx.x;
  int v = (tid < nb) ? bsums[tid] : 0;
  sh[tid] = v; __syncthreads();
  for (int off = 1; off < 64; off <<= 1) {
    int t = (tid >= off) ? sh[tid - off] : 0;
    __syncthreads();
    sh[tid] += t;
    __syncthreads();
  }
  if (tid < nb) bsums[tid] = sh[tid] - v;
}

__global__ void kscan3(const int* __restrict__ bsums, int* __restrict__ part,
                       int* __restrict__ head, int N) {
  int i = blockIdx.x * 1024 + threadIdx.x;
  if (i < N) {
    int v = part[i] + bsums[blockIdx.x];
    part[i] = v;
    head[i] = v;
  }
}

__global__ void kscatter(const int* __restrict__ src, int* __restrict__ head,
                         int* __restrict__ eidx, int E) {
  int e = blockIdx.x * 256 + threadIdx.x;
  if (e < E) {
    int p = atomicAdd(&head[src[e]], 1);
    eidx[p] = e;
  }
}

// Persistent barrier-free edge kernel over SORTED slots; all 4 weight
// matrices LDS-resident; 12 waves/block (3 per SIMD), VGPR cap 170.
__global__ __launch_bounds__(768, 3)
void kedge(const char* __restrict__ hbf, const int* __restrict__ src, const int* __restrict__ dst,
           const float* __restrict__ dist, const float* __restrict__ bpp,
           const float* __restrict__ msa, const float* __restrict__ chem,
           const float* __restrict__ rel, const float* __restrict__ cbm,
           const float* __restrict__ mW1, const float* __restrict__ mb1,
           const float* __restrict__ mW2, const float* __restrict__ mb2,
           const float* __restrict__ cW1, const float* __restrict__ cb1,
           const float* __restrict__ cW2v, const float* __restrict__ cb2,
           const int* __restrict__ eidx, char* __restrict__ m_ij,
           float* __restrict__ coef, int* __restrict__ dsts, int E)
{
  __shared__ short wA0[16384], wA1[16384], wA2[16384], wA3[16384];  // 4 x 32 KB
  __shared__ short wE[2048];
  __shared__ float sb1[128], sb2[128], scb1[128], scw2[128];
  __shared__ float scb2v[1];

  const int tid = threadIdx.x, wid = tid >> 6, lane = tid & 63;
  const int col = lane & 31, hi = lane >> 5;

  stage_w128t<768>(mW1, wA0, tid);
  stage_w128t<768>(mW1 + 16384, wA1, tid);
  stage_w128t<768>(mW2, wA2, tid);
  stage_w128t<768>(cW1, wA3, tid);
  for (int p = tid; p < 2048; p += 768) {
    int j = p >> 4, kk = p & 15;
    float w = (kk < 6) ? mW1[(256 + kk) * 128 + j] : 0.f;
    wE[j * 16 + kk] = (short)(pkbf(w, 0.f) & 0xffffu);
  }
  if (tid < 128) {
    sb1[tid] = mb1[tid]; sb2[tid] = mb2[tid];
    scb1[tid] = cb1[tid]; scw2[tid] = cW2v[tid];
  }
  if (tid == 0) scb2v[0] = cb2[0];
  __syncthreads();

  const int T = (E + 31) / 32;
  const int stride = gridDim.x * 12;
  for (int t = blockIdx.x * 12 + wid; t < T; t += stride) {
    int p = t * 32 + col;               // sorted slot
    bool va = p < E;
    int pc_ = va ? p : E - 1;
    int e = eidx[pc_];
    int s = src[e], d = dst[e];
    float q  = dist[e];
    float f1 = bpp[e], f2 = msa[e], f3 = chem[e], f4 = rel[e], f5 = cbm[e];

    i32x4v bs[8], bd[8];
    #pragma unroll
    for (int kc = 0; kc < 8; ++kc)
      bs[kc] = *(const i32x4v*)(hbf + (size_t)s * 256 + kc * 32 + hi * 16);
    #pragma unroll
    for (int kc = 0; kc < 8; ++kc)
      bd[kc] = *(const i32x4v*)(hbf + (size_t)d * 256 + kc * 32 + hi * 16);

    f32x16 acc[4];
    zacc4(acc);
    #pragma unroll
    for (int kc = 0; kc < 8; ++kc) {
      bf16x8 b = __builtin_bit_cast(bf16x8, bs[kc]);
      #pragma unroll
      for (int jm = 0; jm < 4; ++jm)
        acc[jm] = MFMA32(ldsA(wA0, jm * 32 + col, kc * 16 + hi * 8), b, acc[jm]);
    }
    #pragma unroll
    for (int kc = 0; kc < 8; ++kc) {
      bf16x8 b = __builtin_bit_cast(bf16x8, bd[kc]);
      #pragma unroll
      for (int jm = 0; jm < 4; ++jm)
        acc[jm] = MFMA32(ldsA(wA1, jm * 32 + col, kc * 16 + hi * 8), b, acc[jm]);
    }
    {
      i32x4v ev;
      ev[0] = hi ? 0 : (int)pkbf(q * q, f1);
      ev[1] = hi ? 0 : (int)pkbf(f2, f3);
      ev[2] = hi ? 0 : (int)pkbf(f4, f5);
      ev[3] = 0;
      bf16x8 be = __builtin_bit_cast(bf16x8, ev);
      #pragma unroll
      for (int jm = 0; jm < 4; ++jm) {
        bf16x8 af = __builtin_bit_cast(bf16x8,
            *(const i32x4v*)((const char*)wE + (jm * 32 + col) * 32 + hi * 16));
        acc[jm] = MFMA32(af, be, acc[jm]);
      }
    }

    i32x4v bfr[8];
    trans1(acc, sb1, hi, bfr);

    zacc4(acc);
    #pragma unroll
    for (int kc = 0; kc < 8; ++kc) {
      bf16x8 b = __builtin_bit_cast(bf16x8, bfr[kc]);
      #pragma unroll
      for (int jm = 0; jm < 4; ++jm)
        acc[jm] = MFMA32(ldsA(wA2, jm * 32 + col, kc * 16 + hi * 8), b, acc[jm]);
    }
    // m = silu(t2+b2): store at SORTED slot p (contiguous tiles), repack for c-layer
    trans2s(acc, sb2, hi, bfr, va ? (m_ij + (size_t)p * 256) : nullptr);

    zacc4(acc);
    #pragma unroll
    for (int kc = 0; kc < 8; ++kc) {
      bf16x8 b = __builtin_bit_cast(bf16x8, bfr[kc]);
      #pragma unroll
      for (int jm = 0; jm < 4; ++jm)
        acc[jm] = MFMA32(ldsA(wA3, jm * 32 + col, kc * 16 + hi * 8), b, acc[jm]);
    }
    float part = 0.f;
    #pragma unroll
    for (int jm = 0; jm < 4; ++jm)
      #pragma unroll
      for (int r = 0; r < 16; ++r) {
        int rowloc = (r & 3) + 8 * (r >> 2) + 4 * hi;
        part += silu_f(acc[jm][r] + scb1[jm * 32 + rowloc]) * scw2[jm * 32 + rowloc];
      }
    part += __shfl_xor(part, 32);
    float cf = tanh_f(part + scb2v[0]);
    if (va && hi == 0) {
      coef[p] = cf;
      dsts[p] = d;    // dsts aliases eidx: same slot, read-before-write in this iter
    }
  }
}

// Streaming segmented sum over sorted slots: 16 threads per node, each owns
// 16 bytes (8 dims) of the row. Plus x epilogue.
__global__ __launch_bounds__(256)
void kagg(const char* __restrict__ m_ij, const int* __restrict__ row_start,
          const int* __restrict__ cnt, const float* __restrict__ coef,
          const int* __restrict__ dsts, const float* __restrict__ x,
          char* __restrict__ mibf, float* __restrict__ outX, int N)
{
  int n = blockIdx.x * 16 + (threadIdx.x >> 4);
  int t = threadIdx.x & 15;
  if (n >= N) return;
  int st = row_start[n], c = cnt[n];
  float a[8] = {0.f, 0.f, 0.f, 0.f, 0.f, 0.f, 0.f, 0.f};
  for (int k = 0; k < c; ++k) {
    i32x4v u = *(const i32x4v*)(m_ij + (size_t)(st + k) * 256 + t * 16);
    #pragma unroll
    for (int q = 0; q < 4; ++q) {
      u32 w = (u32)u[q];
      a[q * 2]     += bf2f(w & 0xffffu);
      a[q * 2 + 1] += bf2f(w >> 16);
    }
  }
  float inv = 1.f / fmaxf((float)c, 1.f);
  i32x4v o;
  #pragma unroll
  for (int q = 0; q < 4; ++q) o[q] = (int)pkbf(a[q * 2] * inv, a[q * 2 + 1] * inv);
  *(i32x4v*)(mibf + (size_t)n * 256 + t * 16) = o;
  if (t == 0) {
    float x0 = x[(size_t)n * 3], x1 = x[(size_t)n * 3 + 1], x2 = x[(size_t)n * 3 + 2];
    float dx = 0.f, dy = 0.f, dz = 0.f;
    for (int k = 0; k < c; ++k) {
      float cf = coef[st + k];
      int dn = dsts[st + k];
      dx += (x0 - x[(size_t)dn * 3])     * cf;
      dy += (x1 - x[(size_t)dn * 3 + 1]) * cf;
      dz += (x2 - x[(size_t)dn * 3 + 2]) * cf;
    }
    outX[(size_t)n * 3]     = x0 + dx * inv;
    outX[(size_t)n * 3 + 1] = x1 + dy * inv;
    outX[(size_t)n * 3 + 2] = x2 + dz * inv;
  }
}

// Node MLP layer1: t1h = silu([h | m_i] . hW1 + b1)
__global__ __launch_bounds__(512, 2)
void knode1(const char* __restrict__ hbf, const char* __restrict__ mibf,
            const float* __restrict__ hW1, const float* __restrict__ hb1,
            char* __restrict__ t1h, int N)
{
  __shared__ short wA0[16384], wA1[16384];
  __shared__ float sb1[128];
  const int tid = threadIdx.x, wid = tid >> 6, lane = tid & 63;
  const int col = lane & 31, hi = lane >> 5;
  stage_w128t<512>(hW1, wA0, tid);
  stage_w128t<512>(hW1 + 16384, wA1, tid);
  if (tid < 128) sb1[tid] = hb1[tid];
  __syncthreads();

  int T = (N + 31) / 32;
  int t = blockIdx.x * 8 + wid;
  if (t >= T) return;
  int n = t * 32 + col;
  bool va = n < N;
  int nc = va ? n : N - 1;

  i32x4v bh[8], bm[8];
  #pragma unroll
  for (int kc = 0; kc < 8; ++kc)
    bh[kc] = *(const i32x4v*)(hbf + (size_t)nc * 256 + kc * 32 + hi * 16);
  #pragma unroll
  for (int kc = 0; kc < 8; ++kc)
    bm[kc] = *(const i32x4v*)(mibf + (size_t)nc * 256 + kc * 32 + hi * 16);

  f32x16 acc[4];
  zacc4(acc);
  #pragma unroll
  for (int kc = 0; kc < 8; ++kc) {
    bf16x8 b = __builtin_bit_cast(bf16x8, bh[kc]);
    #pragma unroll
    for (int jm = 0; jm < 4; ++jm)
      acc[jm] = MFMA32(ldsA(wA0, jm * 32 + col, kc * 16 + hi * 8), b, acc[jm]);
  }
  #pragma unroll
  for (int kc = 0; kc < 8; ++kc) {
    bf16x8 b = __builtin_bit_cast(bf16x8, bm[kc]);
    #pragma unroll
    for (int jm = 0; jm < 4; ++jm)
      acc[jm] = MFMA32(ldsA(wA1, jm * 32 + col, kc * 16 + hi * 8), b, acc[jm]);
  }
  #pragma unroll
  for (int jm = 0; jm < 4; ++jm) {
    float v[16];
    #pragma unroll
    for (int r = 0; r < 16; ++r) {
      int rowloc = (r & 3) + 8 * (r >> 2) + 4 * hi;
      v[r] = silu_f(acc[jm][r] + sb1[jm * 32 + rowloc]);
    }
    u32 p0 = pkbf(v[0], v[1]),  p1 = pkbf(v[2], v[3]);
    u32 p2 = pkbf(v[4], v[5]),  p3 = pkbf(v[6], v[7]);
    u32 p4 = pkbf(v[8], v[9]),  p5 = pkbf(v[10], v[11]);
    u32 p6 = pkbf(v[12], v[13]), p7 = pkbf(v[14], v[15]);
    if (va) row_chunks(p0, p1, p2, p3, p4, p5, p6, p7, hi, t1h + (size_t)n * 256, jm);
  }
}

// Node MLP layer2 + residual: h_out = h + t1h . hW2 + b2
__global__ __launch_bounds__(512, 2)
void knode2(const char* __restrict__ t1h, const float* __restrict__ hW2,
            const float* __restrict__ hb2, const float* __restrict__ h,
            float* __restrict__ outH, int N)
{
  __shared__ short wA0[16384];
  __shared__ float sb2[128];
  const int tid = threadIdx.x, wid = tid >> 6, lane = tid & 63;
  const int col = lane & 31, hi = lane >> 5;
  stage_w128t<512>(hW2, wA0, tid);
  if (tid < 128) sb2[tid] = hb2[tid];
  __syncthreads();

  int T = (N + 31) / 32;
  int t = blockIdx.x * 8 + wid;
  if (t >= T) return;
  int n = t * 32 + col;
  bool va = n < N;
  int nc = va ? n : N - 1;

  i32x4v bt[8];
  #pragma unroll
  for (int kc = 0; kc < 8; ++kc)
    bt[kc] = *(const i32x4v*)(t1h + (size_t)nc * 256 + kc * 32 + hi * 16);

  f32x16 acc[4];
  zacc4(acc);
  #pragma unroll
  for (int kc = 0; kc < 8; ++kc) {
    bf16x8 b = __builtin_bit_cast(bf16x8, bt[kc]);
    #pragma unroll
    for (int jm = 0; jm < 4; ++jm)
      acc[jm] = MFMA32(ldsA(wA0, jm * 32 + col, kc * 16 + hi * 8), b, acc[jm]);
  }
  const float4* h4 = (const float4*)h;
  #pragma unroll
  for (int jm = 0; jm < 4; ++jm)
    #pragma unroll
    for (int rq = 0; rq < 4; ++rq) {
      int j0 = jm * 32 + rq * 8 + hi * 4;
      float4 hv = h4[(size_t)nc * 32 + (j0 >> 2)];
      float4 o;
      o.x = hv.x + acc[jm][rq * 4 + 0] + sb2[j0 + 0];
      o.y = hv.y + acc[jm][rq * 4 + 1] + sb2[j0 + 1];
      o.z = hv.z + acc[jm][rq * 4 + 2] + sb2[j0 + 2];
      o.w = hv.w + acc[jm][rq * 4 + 3] + sb2[j0 + 3];
      if (va) ((float4*)outH)[(size_t)nc * 32 + (j0 >> 2)] = o;
    }
}

// ===================== LAUNCH =====================

extern "C" void kernel_launch(void* const* d_in, const int* in_sizes, int n_in,
                              void* d_out, int out_size, void* d_ws, size_t ws_size,
                              hipStream_t stream) {
  const float* h    = (const float*)d_in[0];
  const float* x    = (const float*)d_in[1];
  const int*   src  = (const int*)d_in[2];
  const int*   dst  = (const int*)d_in[3];
  const float* dist = (const float*)d_in[4];
  const float* bpp  = (const float*)d_in[5];
  const float* msa  = (const float*)d_in[6];
  const float* chem = (const float*)d_in[7];
  const float* rel  = (const float*)d_in[8];
  const float* cbm  = (const float*)d_in[9];
  const float* mW1  = (const float*)d_in[10];
  const float* mb1  = (const float*)d_in[11];
  const float* mW2  = (const float*)d_in[12];
  const float* mb2  = (const float*)d_in[13];
  const float* hW1  = (const float*)d_in[14];
  const float* hb1  = (const float*)d_in[15];
  const float* hW2  = (const float*)d_in[16];
  const float* hb2  = (const float*)d_in[17];
  const float* cW1  = (const float*)d_in[18];
  const float* cb1  = (const float*)d_in[19];
  const float* cW2  = (const float*)d_in[20];
  const float* cb2  = (const float*)d_in[21];

  int N = in_sizes[0] / 128;
  int E = in_sizes[2];

  size_t off = 0;
  auto A = [&](size_t b) { size_t o = off; off += (b + 255) & ~(size_t)255; return o; };
  size_t o_cnt  = A((size_t)N * 4);
  size_t o_rs   = A((size_t)N * 4);
  size_t o_head = A((size_t)N * 4);
  size_t o_eidx = A((size_t)E * 4);
  size_t o_coef = A((size_t)E * 4);
  size_t o_bs   = A(1024);
  size_t o_hbf  = A((size_t)N * 256);
  size_t o_mibf = A((size_t)N * 256);
  size_t o_mij  = A((size_t)E * 256);

  char* W = (char*)d_ws;
  int*   cnt32 = (int*)(W + o_cnt);
  int*   rs    = (int*)(W + o_rs);
  int*   head  = (int*)(W + o_head);
  int*   eidx  = (int*)(W + o_eidx);
  float* coef  = (float*)(W + o_coef);
  int*   bsums = (int*)(W + o_bs);
  char*  hbf   = W + o_hbf;
  char*  mibf  = W + o_mibf;
  char*  mij   = W + o_mij;
  char*  t1h   = W + o_mij;   // alias: m_ij consumed by kagg before knode1 writes
  int*   dsts  = eidx;        // alias: eidx[p] read-then-overwritten per slot in kedge

  hipMemsetAsync(cnt32, 0, (size_t)N * 4, stream);
  kconv<<<(N * 16 + 255) / 256, 256, 0, stream>>>(h, hbf, N * 16);
  khist<<<(E + 255) / 256, 256, 0, stream>>>(src, cnt32, E);
  int nb = (N + 1023) / 1024;
  kscan1<<<nb, 1024, 0, stream>>>(cnt32, rs, bsums, N);
  kscan2<<<1, 64, 0, stream>>>(bsums, nb);
  kscan3<<<nb, 1024, 0, stream>>>(bsums, rs, head, N);
  kscatter<<<(E + 255) / 256, 256, 0, stream>>>(src, head, eidx, E);
  kedge<<<256, 768, 0, stream>>>(hbf, src, dst, dist, bpp, msa, chem, rel, cbm,
                                 mW1, mb1, mW2, mb2, cW1, cb1, cW2, cb2,
                                 eidx, mij, coef, dsts, E);
  kagg<<<(N + 15) / 16, 256, 0, stream>>>(mij, rs, cnt32, coef, dsts, x,
                                          mibf, (float*)d_out + (size_t)N * 128, N);
  int tb = ((N + 31) / 32 + 7) / 8;
  knode1<<<tb, 512, 0, stream>>>(hbf, mibf, hW1, hb1, t1h, N);
  knode2<<<tb, 512, 0, stream>>>(t1h, hW2, hb2, h, (float*)d_out, N);
}

// Round 5
// 1029.307 us; speedup vs baseline: 1.1339x; 1.0490x over previous
//
#include <hip/hip_runtime.h>
#include <hip/hip_bf16.h>

typedef short bf16x8 __attribute__((ext_vector_type(8)));
typedef float f32x16 __attribute__((ext_vector_type(16)));
typedef int   i32x4v __attribute__((ext_vector_type(4)));
typedef unsigned u32;

#define MFMA32(a,b,c) __builtin_amdgcn_mfma_f32_32x32x16_bf16((a),(b),(c),0,0,0)

__device__ __forceinline__ u32 pkbf(float x, float y) {
  union { u32 u; __hip_bfloat16 h[2]; } t;
  t.h[0] = __float2bfloat16(x);
  t.h[1] = __float2bfloat16(y);
  return t.u;
}
__device__ __forceinline__ float bf2f(u32 lo16) {
  union { u32 u; float f; } t; t.u = lo16 << 16; return t.f;
}
__device__ __forceinline__ float silu_f(float v) { return v / (1.f + __expf(-v)); }
__device__ __forceinline__ float tanh_f(float v) {
  float e = __expf(2.f * fabsf(v));
  float t = 1.f - 2.f / (e + 1.f);
  return copysignf(t, v);
}

// Stage [128][128] f32 weight block (row k = in, col j = out) into LDS
// transposed bf16 wA[j][k] with 16B-unit XOR swizzle.
template<int NT>
__device__ __forceinline__ void stage_w128t(const float* __restrict__ W, short* wA, int tid) {
  for (int p = tid; p < 8192; p += NT) {
    int j = p & 127;
    int k = (p >> 7) << 1;
    u32 u = pkbf(W[k * 128 + j], W[k * 128 + 128 + j]);
    int off = j * 256 + (((k >> 3) ^ (j & 15)) << 4) + ((k & 7) << 1);
    *(u32*)((char*)wA + off) = u;
  }
}
__device__ __forceinline__ bf16x8 ldsA(const short* wA, int j, int kbase) {
  int off = j * 256 + (((kbase >> 3) ^ (j & 15)) << 4);
  return __builtin_bit_cast(bf16x8, *(const i32x4v*)((const char*)wA + off));
}

__device__ __forceinline__ void zacc4(f32x16 (&acc)[4]) {
  #pragma unroll
  for (int jm = 0; jm < 4; ++jm)
    #pragma unroll
    for (int r = 0; r < 16; ++r) acc[jm][r] = 0.f;
}

// Store one jm-block (32 dims) of a row as 2x16B contiguous chunks per lane,
// after a hi-pair exchange. p0..p7 are bf16 pairs of v[0..15] in C-layout order.
__device__ __forceinline__ void row_chunks(u32 p0, u32 p1, u32 p2, u32 p3,
                                           u32 p4, u32 p5, u32 p6, u32 p7,
                                           int hi, char* rowptr, int jm) {
  u32 x0 = (u32)__shfl_xor((int)(hi ? p0 : p4), 32);
  u32 x1 = (u32)__shfl_xor((int)(hi ? p1 : p5), 32);
  u32 x2 = (u32)__shfl_xor((int)(hi ? p2 : p6), 32);
  u32 x3 = (u32)__shfl_xor((int)(hi ? p3 : p7), 32);
  i32x4v c0, c1;
  if (hi) {
    c0[0] = (int)x0; c0[1] = (int)x1; c0[2] = (int)p4; c0[3] = (int)p5;
    c1[0] = (int)x2; c1[1] = (int)x3; c1[2] = (int)p6; c1[3] = (int)p7;
  } else {
    c0[0] = (int)p0; c0[1] = (int)p1; c0[2] = (int)x0; c0[3] = (int)x1;
    c1[0] = (int)p2; c1[1] = (int)p3; c1[2] = (int)x2; c1[3] = (int)x3;
  }
  *(i32x4v*)(rowptr + jm * 64 + hi * 32)      = c0;
  *(i32x4v*)(rowptr + jm * 64 + hi * 32 + 16) = c1;
}

// C-layout -> silu(+bias) -> bf16 B-fragments for next K=128 GEMM (in-place b reuse).
__device__ __forceinline__ void trans1(f32x16 (&acc)[4], const float* bias, int hi,
                                       i32x4v (&bfr)[8]) {
  #pragma unroll
  for (int jm = 0; jm < 4; ++jm) {
    float v[16];
    #pragma unroll
    for (int r = 0; r < 16; ++r) {
      int rowloc = (r & 3) + 8 * (r >> 2) + 4 * hi;
      v[r] = silu_f(acc[jm][r] + bias[jm * 32 + rowloc]);
    }
    #pragma unroll
    for (int blk = 0; blk < 2; ++blk) {
      int r0 = blk * 8;
      u32 pa = pkbf(v[r0 + 0], v[r0 + 1]);
      u32 pb = pkbf(v[r0 + 2], v[r0 + 3]);
      u32 pc = pkbf(v[r0 + 4], v[r0 + 5]);
      u32 pd = pkbf(v[r0 + 6], v[r0 + 7]);
      u32 g1 = (u32)__shfl_xor((int)(hi ? pa : pc), 32);
      u32 g2 = (u32)__shfl_xor((int)(hi ? pb : pd), 32);
      i32x4v w;
      w[0] = hi ? (int)g1 : (int)pa;
      w[1] = hi ? (int)g2 : (int)pb;
      w[2] = hi ? (int)pc : (int)g1;
      w[3] = hi ? (int)pd : (int)g2;
      bfr[jm * 2 + blk] = w;
    }
  }
}

// Same, plus contiguous-chunk row store (sorted slot layout).
__device__ __forceinline__ void trans2s(f32x16 (&acc)[4], const float* bias, int hi,
                                        i32x4v (&bfr)[8], char* rowptr) {
  #pragma unroll
  for (int jm = 0; jm < 4; ++jm) {
    float v[16];
    #pragma unroll
    for (int r = 0; r < 16; ++r) {
      int rowloc = (r & 3) + 8 * (r >> 2) + 4 * hi;
      v[r] = silu_f(acc[jm][r] + bias[jm * 32 + rowloc]);
    }
    u32 p0 = pkbf(v[0], v[1]),  p1 = pkbf(v[2], v[3]);
    u32 p2 = pkbf(v[4], v[5]),  p3 = pkbf(v[6], v[7]);
    u32 p4 = pkbf(v[8], v[9]),  p5 = pkbf(v[10], v[11]);
    u32 p6 = pkbf(v[12], v[13]), p7 = pkbf(v[14], v[15]);
    {
      u32 g1 = (u32)__shfl_xor((int)(hi ? p0 : p2), 32);
      u32 g2 = (u32)__shfl_xor((int)(hi ? p1 : p3), 32);
      i32x4v w;
      w[0] = hi ? (int)g1 : (int)p0;
      w[1] = hi ? (int)g2 : (int)p1;
      w[2] = hi ? (int)p2 : (int)g1;
      w[3] = hi ? (int)p3 : (int)g2;
      bfr[jm * 2] = w;
      u32 g1b = (u32)__shfl_xor((int)(hi ? p4 : p6), 32);
      u32 g2b = (u32)__shfl_xor((int)(hi ? p5 : p7), 32);
      i32x4v w2;
      w2[0] = hi ? (int)g1b : (int)p4;
      w2[1] = hi ? (int)g2b : (int)p5;
      w2[2] = hi ? (int)p6 : (int)g1b;
      w2[3] = hi ? (int)p7 : (int)g2b;
      bfr[jm * 2 + 1] = w2;
    }
    if (rowptr) row_chunks(p0, p1, p2, p3, p4, p5, p6, p7, hi, rowptr, jm);
  }
}

// ===================== PIPELINE =====================

__global__ void kconv(const float* __restrict__ h, char* __restrict__ hbf, int total16) {
  int i = blockIdx.x * 256 + threadIdx.x;
  if (i >= total16) return;
  const float4* h4 = (const float4*)h;
  float4 a = h4[(size_t)i * 2], b = h4[(size_t)i * 2 + 1];
  i32x4v w;
  w[0] = (int)pkbf(a.x, a.y); w[1] = (int)pkbf(a.z, a.w);
  w[2] = (int)pkbf(b.x, b.y); w[3] = (int)pkbf(b.z, b.w);
  *(i32x4v*)(hbf + (size_t)i * 16) = w;
}

__global__ void khist(const int* __restrict__ src, int* __restrict__ cnt, int E) {
  int e = blockIdx.x * 256 + threadIdx.x;
  if (e < E) atomicAdd(&cnt[src[e]], 1);
}

__global__ void kscan1(const int* __restrict__ cnt, int* __restrict__ part,
                       int* __restrict__ bsums, int N) {
  __shared__ int sh[1024];
  int tid = threadIdx.x, i = blockIdx.x * 1024 + tid;
  int v = (i < N) ? cnt[i] : 0;
  sh[tid] = v; __syncthreads();
  for (int off = 1; off < 1024; off <<= 1) {
    int t = (tid >= off) ? sh[tid - off] : 0;
    __syncthreads();
    sh[tid] += t;
    __syncthreads();
  }
  if (i < N) part[i] = sh[tid] - v;
  if (tid == 1023) bsums[blockIdx.x] = sh[1023];
}

__global__ void kscan2(int* __restrict__ bsums, int nb) {
  __shared__ int sh[64];
  int tid = threadIdx.x;
  int v = (tid < nb) ? bsums[tid] : 0;
  sh[tid] = v; __syncthreads();
  for (int off = 1; off < 64; off <<= 1) {
    int t = (tid >= off) ? sh[tid - off] : 0;
    __syncthreads();
    sh[tid] += t;
    __syncthreads();
  }
  if (tid < nb) bsums[tid] = sh[tid] - v;
}

__global__ void kscan3(const int* __restrict__ bsums, int* __restrict__ part,
                       int* __restrict__ head, int N) {
  int i = blockIdx.x * 1024 + threadIdx.x;
  if (i < N) {
    int v = part[i] + bsums[blockIdx.x];
    part[i] = v;
    head[i] = v;
  }
}

__global__ void kscatter(const int* __restrict__ src, int* __restrict__ head,
                         int* __restrict__ eidx, int E) {
  int e = blockIdx.x * 256 + threadIdx.x;
  if (e < E) {
    int p = atomicAdd(&head[src[e]], 1);
    eidx[p] = e;
  }
}

// Persistent barrier-free edge kernel over SORTED slots; all 4 weight
// matrices LDS-resident. 512 thr / (512,2): compiler picks 128 VGPRs (r2-
// proven); single b[8] buffer reused for src-rows/dst-rows/bfr keeps peak
// demand ~120 -> no scratch spills.
__global__ __launch_bounds__(512, 2)
void kedge(const char* __restrict__ hbf, const int* __restrict__ src, const int* __restrict__ dst,
           const float* __restrict__ dist, const float* __restrict__ bpp,
           const float* __restrict__ msa, const float* __restrict__ chem,
           const float* __restrict__ rel, const float* __restrict__ cbm,
           const float* __restrict__ mW1, const float* __restrict__ mb1,
           const float* __restrict__ mW2, const float* __restrict__ mb2,
           const float* __restrict__ cW1, const float* __restrict__ cb1,
           const float* __restrict__ cW2v, const float* __restrict__ cb2,
           const int* __restrict__ eidx, char* __restrict__ m_ij,
           float* __restrict__ coef, int* __restrict__ dsts, int E)
{
  __shared__ short wA0[16384], wA1[16384], wA2[16384], wA3[16384];  // 4 x 32 KB
  __shared__ short wE[2048];
  __shared__ float sb1[128], sb2[128], scb1[128], scw2[128];
  __shared__ float scb2v[1];

  const int tid = threadIdx.x, wid = tid >> 6, lane = tid & 63;
  const int col = lane & 31, hi = lane >> 5;

  stage_w128t<512>(mW1, wA0, tid);
  stage_w128t<512>(mW1 + 16384, wA1, tid);
  stage_w128t<512>(mW2, wA2, tid);
  stage_w128t<512>(cW1, wA3, tid);
  for (int p = tid; p < 2048; p += 512) {
    int j = p >> 4, kk = p & 15;
    float w = (kk < 6) ? mW1[(256 + kk) * 128 + j] : 0.f;
    wE[j * 16 + kk] = (short)(pkbf(w, 0.f) & 0xffffu);
  }
  if (tid < 128) {
    sb1[tid] = mb1[tid]; sb2[tid] = mb2[tid];
    scb1[tid] = cb1[tid]; scw2[tid] = cW2v[tid];
  }
  if (tid == 0) scb2v[0] = cb2[0];
  __syncthreads();

  const int T = (E + 31) / 32;
  const int stride = gridDim.x * 8;
  for (int t = blockIdx.x * 8 + wid; t < T; t += stride) {
    int p = t * 32 + col;               // sorted slot
    bool va = p < E;
    int pc_ = va ? p : E - 1;
    int e = eidx[pc_];
    int s = src[e], d = dst[e];
    float q  = dist[e];
    float f1 = bpp[e], f2 = msa[e], f3 = chem[e], f4 = rel[e], f5 = cbm[e];

    // single reusable fragment buffer (32 VGPRs): src rows -> dst rows -> bfr
    i32x4v b[8];
    #pragma unroll
    for (int kc = 0; kc < 8; ++kc)
      b[kc] = *(const i32x4v*)(hbf + (size_t)s * 256 + kc * 32 + hi * 16);

    f32x16 acc[4];
    zacc4(acc);
    // GEMM1a (h_src . W1a), interleaving dst-row loads into freed chunks
    #pragma unroll
    for (int kc = 0; kc < 8; ++kc) {
      bf16x8 bb = __builtin_bit_cast(bf16x8, b[kc]);
      b[kc] = *(const i32x4v*)(hbf + (size_t)d * 256 + kc * 32 + hi * 16);
      #pragma unroll
      for (int jm = 0; jm < 4; ++jm)
        acc[jm] = MFMA32(ldsA(wA0, jm * 32 + col, kc * 16 + hi * 8), bb, acc[jm]);
    }
    // GEMM1b (h_dst . W1b)
    #pragma unroll
    for (int kc = 0; kc < 8; ++kc) {
      bf16x8 bb = __builtin_bit_cast(bf16x8, b[kc]);
      #pragma unroll
      for (int jm = 0; jm < 4; ++jm)
        acc[jm] = MFMA32(ldsA(wA1, jm * 32 + col, kc * 16 + hi * 8), bb, acc[jm]);
    }
    // extras chunk (k 256..261 padded)
    {
      i32x4v ev;
      ev[0] = hi ? 0 : (int)pkbf(q * q, f1);
      ev[1] = hi ? 0 : (int)pkbf(f2, f3);
      ev[2] = hi ? 0 : (int)pkbf(f4, f5);
      ev[3] = 0;
      bf16x8 be = __builtin_bit_cast(bf16x8, ev);
      #pragma unroll
      for (int jm = 0; jm < 4; ++jm) {
        bf16x8 af = __builtin_bit_cast(bf16x8,
            *(const i32x4v*)((const char*)wE + (jm * 32 + col) * 32 + hi * 16));
        acc[jm] = MFMA32(af, be, acc[jm]);
      }
    }

    trans1(acc, sb1, hi, b);      // b <- layer2 B-fragments

    zacc4(acc);
    #pragma unroll
    for (int kc = 0; kc < 8; ++kc) {
      bf16x8 bb = __builtin_bit_cast(bf16x8, b[kc]);
      #pragma unroll
      for (int jm = 0; jm < 4; ++jm)
        acc[jm] = MFMA32(ldsA(wA2, jm * 32 + col, kc * 16 + hi * 8), bb, acc[jm]);
    }
    // m = silu(t2+b2): store at SORTED slot p (contiguous tiles), b <- c-layer frags
    trans2s(acc, sb2, hi, b, va ? (m_ij + (size_t)p * 256) : nullptr);

    zacc4(acc);
    #pragma unroll
    for (int kc = 0; kc < 8; ++kc) {
      bf16x8 bb = __builtin_bit_cast(bf16x8, b[kc]);
      #pragma unroll
      for (int jm = 0; jm < 4; ++jm)
        acc[jm] = MFMA32(ldsA(wA3, jm * 32 + col, kc * 16 + hi * 8), bb, acc[jm]);
    }
    float part = 0.f;
    #pragma unroll
    for (int jm = 0; jm < 4; ++jm)
      #pragma unroll
      for (int r = 0; r < 16; ++r) {
        int rowloc = (r & 3) + 8 * (r >> 2) + 4 * hi;
        part += silu_f(acc[jm][r] + scb1[jm * 32 + rowloc]) * scw2[jm * 32 + rowloc];
      }
    part += __shfl_xor(part, 32);
    float cf = tanh_f(part + scb2v[0]);
    if (va && hi == 0) {
      coef[p] = cf;
      dsts[p] = d;    // dsts aliases eidx: same slot, read-before-write in this iter
    }
  }
}

// Streaming segmented sum over sorted slots: 16 threads per node, each owns
// 16 bytes (8 dims) of the row. Plus x epilogue.
__global__ __launch_bounds__(256)
void kagg(const char* __restrict__ m_ij, const int* __restrict__ row_start,
          const int* __restrict__ cnt, const float* __restrict__ coef,
          const int* __restrict__ dsts, const float* __restrict__ x,
          char* __restrict__ mibf, float* __restrict__ outX, int N)
{
  int n = blockIdx.x * 16 + (threadIdx.x >> 4);
  int t = threadIdx.x & 15;
  if (n >= N) return;
  int st = row_start[n], c = cnt[n];
  float a[8] = {0.f, 0.f, 0.f, 0.f, 0.f, 0.f, 0.f, 0.f};
  for (int k = 0; k < c; ++k) {
    i32x4v u = *(const i32x4v*)(m_ij + (size_t)(st + k) * 256 + t * 16);
    #pragma unroll
    for (int q = 0; q < 4; ++q) {
      u32 w = (u32)u[q];
      a[q * 2]     += bf2f(w & 0xffffu);
      a[q * 2 + 1] += bf2f(w >> 16);
    }
  }
  float inv = 1.f / fmaxf((float)c, 1.f);
  i32x4v o;
  #pragma unroll
  for (int q = 0; q < 4; ++q) o[q] = (int)pkbf(a[q * 2] * inv, a[q * 2 + 1] * inv);
  *(i32x4v*)(mibf + (size_t)n * 256 + t * 16) = o;
  if (t == 0) {
    float x0 = x[(size_t)n * 3], x1 = x[(size_t)n * 3 + 1], x2 = x[(size_t)n * 3 + 2];
    float dx = 0.f, dy = 0.f, dz = 0.f;
    for (int k = 0; k < c; ++k) {
      float cf = coef[st + k];
      int dn = dsts[st + k];
      dx += (x0 - x[(size_t)dn * 3])     * cf;
      dy += (x1 - x[(size_t)dn * 3 + 1]) * cf;
      dz += (x2 - x[(size_t)dn * 3 + 2]) * cf;
    }
    outX[(size_t)n * 3]     = x0 + dx * inv;
    outX[(size_t)n * 3 + 1] = x1 + dy * inv;
    outX[(size_t)n * 3 + 2] = x2 + dz * inv;
  }
}

// Node MLP layer1: t1h = silu([h | m_i] . hW1 + b1)
__global__ __launch_bounds__(512, 2)
void knode1(const char* __restrict__ hbf, const char* __restrict__ mibf,
            const float* __restrict__ hW1, const float* __restrict__ hb1,
            char* __restrict__ t1h, int N)
{
  __shared__ short wA0[16384], wA1[16384];
  __shared__ float sb1[128];
  const int tid = threadIdx.x, wid = tid >> 6, lane = tid & 63;
  const int col = lane & 31, hi = lane >> 5;
  stage_w128t<512>(hW1, wA0, tid);
  stage_w128t<512>(hW1 + 16384, wA1, tid);
  if (tid < 128) sb1[tid] = hb1[tid];
  __syncthreads();

  int T = (N + 31) / 32;
  int t = blockIdx.x * 8 + wid;
  if (t >= T) return;
  int n = t * 32 + col;
  bool va = n < N;
  int nc = va ? n : N - 1;

  i32x4v b[8];
  #pragma unroll
  for (int kc = 0; kc < 8; ++kc)
    b[kc] = *(const i32x4v*)(hbf + (size_t)nc * 256 + kc * 32 + hi * 16);

  f32x16 acc[4];
  zacc4(acc);
  #pragma unroll
  for (int kc = 0; kc < 8; ++kc) {
    bf16x8 bb = __builtin_bit_cast(bf16x8, b[kc]);
    b[kc] = *(const i32x4v*)(mibf + (size_t)nc * 256 + kc * 32 + hi * 16);
    #pragma unroll
    for (int jm = 0; jm < 4; ++jm)
      acc[jm] = MFMA32(ldsA(wA0, jm * 32 + col, kc * 16 + hi * 8), bb, acc[jm]);
  }
  #pragma unroll
  for (int kc = 0; kc < 8; ++kc) {
    bf16x8 bb = __builtin_bit_cast(bf16x8, b[kc]);
    #pragma unroll
    for (int jm = 0; jm < 4; ++jm)
      acc[jm] = MFMA32(ldsA(wA1, jm * 32 + col, kc * 16 + hi * 8), bb, acc[jm]);
  }
  #pragma unroll
  for (int jm = 0; jm < 4; ++jm) {
    float v[16];
    #pragma unroll
    for (int r = 0; r < 16; ++r) {
      int rowloc = (r & 3) + 8 * (r >> 2) + 4 * hi;
      v[r] = silu_f(acc[jm][r] + sb1[jm * 32 + rowloc]);
    }
    u32 p0 = pkbf(v[0], v[1]),  p1 = pkbf(v[2], v[3]);
    u32 p2 = pkbf(v[4], v[5]),  p3 = pkbf(v[6], v[7]);
    u32 p4 = pkbf(v[8], v[9]),  p5 = pkbf(v[10], v[11]);
    u32 p6 = pkbf(v[12], v[13]), p7 = pkbf(v[14], v[15]);
    if (va) row_chunks(p0, p1, p2, p3, p4, p5, p6, p7, hi, t1h + (size_t)n * 256, jm);
  }
}

// Node MLP layer2 + residual: h_out = h + t1h . hW2 + b2
__global__ __launch_bounds__(512, 2)
void knode2(const char* __restrict__ t1h, const float* __restrict__ hW2,
            const float* __restrict__ hb2, const float* __restrict__ h,
            float* __restrict__ outH, int N)
{
  __shared__ short wA0[16384];
  __shared__ float sb2[128];
  const int tid = threadIdx.x, wid = tid >> 6, lane = tid & 63;
  const int col = lane & 31, hi = lane >> 5;
  stage_w128t<512>(hW2, wA0, tid);
  if (tid < 128) sb2[tid] = hb2[tid];
  __syncthreads();

  int T = (N + 31) / 32;
  int t = blockIdx.x * 8 + wid;
  if (t >= T) return;
  int n = t * 32 + col;
  bool va = n < N;
  int nc = va ? n : N - 1;

  i32x4v b[8];
  #pragma unroll
  for (int kc = 0; kc < 8; ++kc)
    b[kc] = *(const i32x4v*)(t1h + (size_t)nc * 256 + kc * 32 + hi * 16);

  f32x16 acc[4];
  zacc4(acc);
  #pragma unroll
  for (int kc = 0; kc < 8; ++kc) {
    bf16x8 bb = __builtin_bit_cast(bf16x8, b[kc]);
    #pragma unroll
    for (int jm = 0; jm < 4; ++jm)
      acc[jm] = MFMA32(ldsA(wA0, jm * 32 + col, kc * 16 + hi * 8), bb, acc[jm]);
  }
  const float4* h4 = (const float4*)h;
  #pragma unroll
  for (int jm = 0; jm < 4; ++jm)
    #pragma unroll
    for (int rq = 0; rq < 4; ++rq) {
      int j0 = jm * 32 + rq * 8 + hi * 4;
      float4 hv = h4[(size_t)nc * 32 + (j0 >> 2)];
      float4 o;
      o.x = hv.x + acc[jm][rq * 4 + 0] + sb2[j0 + 0];
      o.y = hv.y + acc[jm][rq * 4 + 1] + sb2[j0 + 1];
      o.z = hv.z + acc[jm][rq * 4 + 2] + sb2[j0 + 2];
      o.w = hv.w + acc[jm][rq * 4 + 3] + sb2[j0 + 3];
      if (va) ((float4*)outH)[(size_t)nc * 32 + (j0 >> 2)] = o;
    }
}

// ===================== LAUNCH =====================

extern "C" void kernel_launch(void* const* d_in, const int* in_sizes, int n_in,
                              void* d_out, int out_size, void* d_ws, size_t ws_size,
                              hipStream_t stream) {
  const float* h    = (const float*)d_in[0];
  const float* x    = (const float*)d_in[1];
  const int*   src  = (const int*)d_in[2];
  const int*   dst  = (const int*)d_in[3];
  const float* dist = (const float*)d_in[4];
  const float* bpp  = (const float*)d_in[5];
  const float* msa  = (const float*)d_in[6];
  const float* chem = (const float*)d_in[7];
  const float* rel  = (const float*)d_in[8];
  const float* cbm  = (const float*)d_in[9];
  const float* mW1  = (const float*)d_in[10];
  const float* mb1  = (const float*)d_in[11];
  const float* mW2  = (const float*)d_in[12];
  const float* mb2  = (const float*)d_in[13];
  const float* hW1  = (const float*)d_in[14];
  const float* hb1  = (const float*)d_in[15];
  const float* hW2  = (const float*)d_in[16];
  const float* hb2  = (const float*)d_in[17];
  const float* cW1  = (const float*)d_in[18];
  const float* cb1  = (const float*)d_in[19];
  const float* cW2  = (const float*)d_in[20];
  const float* cb2  = (const float*)d_in[21];

  int N = in_sizes[0] / 128;
  int E = in_sizes[2];

  size_t off = 0;
  auto A = [&](size_t b) { size_t o = off; off += (b + 255) & ~(size_t)255; return o; };
  size_t o_cnt  = A((size_t)N * 4);
  size_t o_rs   = A((size_t)N * 4);
  size_t o_head = A((size_t)N * 4);
  size_t o_eidx = A((size_t)E * 4);
  size_t o_coef = A((size_t)E * 4);
  size_t o_bs   = A(1024);
  size_t o_hbf  = A((size_t)N * 256);
  size_t o_mibf = A((size_t)N * 256);
  size_t o_mij  = A((size_t)E * 256);

  char* W = (char*)d_ws;
  int*   cnt32 = (int*)(W + o_cnt);
  int*   rs    = (int*)(W + o_rs);
  int*   head  = (int*)(W + o_head);
  int*   eidx  = (int*)(W + o_eidx);
  float* coef  = (float*)(W + o_coef);
  int*   bsums = (int*)(W + o_bs);
  char*  hbf   = W + o_hbf;
  char*  mibf  = W + o_mibf;
  char*  mij   = W + o_mij;
  char*  t1h   = W + o_mij;   // alias: m_ij consumed by kagg before knode1 writes
  int*   dsts  = eidx;        // alias: eidx[p] read-then-overwritten per slot in kedge

  hipMemsetAsync(cnt32, 0, (size_t)N * 4, stream);
  kconv<<<(N * 16 + 255) / 256, 256, 0, stream>>>(h, hbf, N * 16);
  khist<<<(E + 255) / 256, 256, 0, stream>>>(src, cnt32, E);
  int nb = (N + 1023) / 1024;
  kscan1<<<nb, 1024, 0, stream>>>(cnt32, rs, bsums, N);
  kscan2<<<1, 64, 0, stream>>>(bsums, nb);
  kscan3<<<nb, 1024, 0, stream>>>(bsums, rs, head, N);
  kscatter<<<(E + 255) / 256, 256, 0, stream>>>(src, head, eidx, E);
  kedge<<<256, 512, 0, stream>>>(hbf, src, dst, dist, bpp, msa, chem, rel, cbm,
                                 mW1, mb1, mW2, mb2, cW1, cb1, cW2, cb2,
                                 eidx, mij, coef, dsts, E);
  kagg<<<(N + 15) / 16, 256, 0, stream>>>(mij, rs, cnt32, coef, dsts, x,
                                          mibf, (float*)d_out + (size_t)N * 128, N);
  int tb = ((N + 31) / 32 + 7) / 8;
  knode1<<<tb, 512, 0, stream>>>(hbf, mibf, hW1, hb1, t1h, N);
  knode2<<<tb, 512, 0, stream>>>(t1h, hW2, hb2, h, (float*)d_out, N);
}

// Round 6
// 985.741 us; speedup vs baseline: 1.1840x; 1.0442x over previous
//
#include <hip/hip_runtime.h>
#include <hip/hip_bf16.h>

typedef short bf16x8 __attribute__((ext_vector_type(8)));
typedef float f32x16 __attribute__((ext_vector_type(16)));
typedef int   i32x4v __attribute__((ext_vector_type(4)));
typedef unsigned u32;

#define MFMA32(a,b,c) __builtin_amdgcn_mfma_f32_32x32x16_bf16((a),(b),(c),0,0,0)

__device__ __forceinline__ u32 pkbf(float x, float y) {
  union { u32 u; __hip_bfloat16 h[2]; } t;
  t.h[0] = __float2bfloat16(x);
  t.h[1] = __float2bfloat16(y);
  return t.u;
}
__device__ __forceinline__ float bf2f(u32 lo16) {
  union { u32 u; float f; } t; t.u = lo16 << 16; return t.f;
}
__device__ __forceinline__ float silu_f(float v) { return v / (1.f + __expf(-v)); }
__device__ __forceinline__ float tanh_f(float v) {
  float e = __expf(2.f * fabsf(v));
  float t = 1.f - 2.f / (e + 1.f);
  return copysignf(t, v);
}

// Stage [128][128] f32 weight block (row k = in, col j = out) into LDS
// transposed bf16 wA[j][k] with 16B-unit XOR swizzle.
template<int NT>
__device__ __forceinline__ void stage_w128t(const float* __restrict__ W, short* wA, int tid) {
  for (int p = tid; p < 8192; p += NT) {
    int j = p & 127;
    int k = (p >> 7) << 1;
    u32 u = pkbf(W[k * 128 + j], W[k * 128 + 128 + j]);
    int off = j * 256 + (((k >> 3) ^ (j & 15)) << 4) + ((k & 7) << 1);
    *(u32*)((char*)wA + off) = u;
  }
}
__device__ __forceinline__ bf16x8 ldsA(const short* wA, int j, int kbase) {
  int off = j * 256 + (((kbase >> 3) ^ (j & 15)) << 4);
  return __builtin_bit_cast(bf16x8, *(const i32x4v*)((const char*)wA + off));
}

__device__ __forceinline__ void zacc4(f32x16 (&acc)[4]) {
  #pragma unroll
  for (int jm = 0; jm < 4; ++jm)
    #pragma unroll
    for (int r = 0; r < 16; ++r) acc[jm][r] = 0.f;
}

// Store one jm-block (32 dims) of a row as 2x16B contiguous chunks per lane,
// after a hi-pair exchange. Layout matches the kc*32+hi*16 B-fragment loads
// (proven by knode1->knode2 round trip since r2).
__device__ __forceinline__ void row_chunks(u32 p0, u32 p1, u32 p2, u32 p3,
                                           u32 p4, u32 p5, u32 p6, u32 p7,
                                           int hi, char* rowptr, int jm) {
  u32 x0 = (u32)__shfl_xor((int)(hi ? p0 : p4), 32);
  u32 x1 = (u32)__shfl_xor((int)(hi ? p1 : p5), 32);
  u32 x2 = (u32)__shfl_xor((int)(hi ? p2 : p6), 32);
  u32 x3 = (u32)__shfl_xor((int)(hi ? p3 : p7), 32);
  i32x4v c0, c1;
  if (hi) {
    c0[0] = (int)x0; c0[1] = (int)x1; c0[2] = (int)p4; c0[3] = (int)p5;
    c1[0] = (int)x2; c1[1] = (int)x3; c1[2] = (int)p6; c1[3] = (int)p7;
  } else {
    c0[0] = (int)p0; c0[1] = (int)p1; c0[2] = (int)x0; c0[3] = (int)x1;
    c1[0] = (int)p2; c1[1] = (int)p3; c1[2] = (int)x2; c1[3] = (int)x3;
  }
  *(i32x4v*)(rowptr + jm * 64 + hi * 32)      = c0;
  *(i32x4v*)(rowptr + jm * 64 + hi * 32 + 16) = c1;
}

// C-layout -> silu(+bias) -> row store ONLY (kedgeA epilogue).
__device__ __forceinline__ void trans_store(f32x16 (&acc)[4], const float* bias, int hi,
                                            char* rowptr, bool va) {
  #pragma unroll
  for (int jm = 0; jm < 4; ++jm) {
    float v[16];
    #pragma unroll
    for (int r = 0; r < 16; ++r) {
      int rowloc = (r & 3) + 8 * (r >> 2) + 4 * hi;
      v[r] = silu_f(acc[jm][r] + bias[jm * 32 + rowloc]);
    }
    u32 p0 = pkbf(v[0], v[1]),  p1 = pkbf(v[2], v[3]);
    u32 p2 = pkbf(v[4], v[5]),  p3 = pkbf(v[6], v[7]);
    u32 p4 = pkbf(v[8], v[9]),  p5 = pkbf(v[10], v[11]);
    u32 p6 = pkbf(v[12], v[13]), p7 = pkbf(v[14], v[15]);
    if (va) row_chunks(p0, p1, p2, p3, p4, p5, p6, p7, hi, rowptr, jm);
  }
}

// C-layout -> silu(+bias) -> bfr frags + row store (kedgeB, m store).
__device__ __forceinline__ void trans2s(f32x16 (&acc)[4], const float* bias, int hi,
                                        i32x4v (&bfr)[8], char* rowptr, bool va) {
  #pragma unroll
  for (int jm = 0; jm < 4; ++jm) {
    float v[16];
    #pragma unroll
    for (int r = 0; r < 16; ++r) {
      int rowloc = (r & 3) + 8 * (r >> 2) + 4 * hi;
      v[r] = silu_f(acc[jm][r] + bias[jm * 32 + rowloc]);
    }
    u32 p0 = pkbf(v[0], v[1]),  p1 = pkbf(v[2], v[3]);
    u32 p2 = pkbf(v[4], v[5]),  p3 = pkbf(v[6], v[7]);
    u32 p4 = pkbf(v[8], v[9]),  p5 = pkbf(v[10], v[11]);
    u32 p6 = pkbf(v[12], v[13]), p7 = pkbf(v[14], v[15]);
    {
      u32 g1 = (u32)__shfl_xor((int)(hi ? p0 : p2), 32);
      u32 g2 = (u32)__shfl_xor((int)(hi ? p1 : p3), 32);
      i32x4v w;
      w[0] = hi ? (int)g1 : (int)p0;
      w[1] = hi ? (int)g2 : (int)p1;
      w[2] = hi ? (int)p2 : (int)g1;
      w[3] = hi ? (int)p3 : (int)g2;
      bfr[jm * 2] = w;
      u32 g1b = (u32)__shfl_xor((int)(hi ? p4 : p6), 32);
      u32 g2b = (u32)__shfl_xor((int)(hi ? p5 : p7), 32);
      i32x4v w2;
      w2[0] = hi ? (int)g1b : (int)p4;
      w2[1] = hi ? (int)g2b : (int)p5;
      w2[2] = hi ? (int)p6 : (int)g1b;
      w2[3] = hi ? (int)p7 : (int)g2b;
      bfr[jm * 2 + 1] = w2;
    }
    if (va) row_chunks(p0, p1, p2, p3, p4, p5, p6, p7, hi, rowptr, jm);
  }
}

// ===================== PIPELINE =====================

__global__ void kconv(const float* __restrict__ h, char* __restrict__ hbf, int total16) {
  int i = blockIdx.x * 256 + threadIdx.x;
  if (i >= total16) return;
  const float4* h4 = (const float4*)h;
  float4 a = h4[(size_t)i * 2], b = h4[(size_t)i * 2 + 1];
  i32x4v w;
  w[0] = (int)pkbf(a.x, a.y); w[1] = (int)pkbf(a.z, a.w);
  w[2] = (int)pkbf(b.x, b.y); w[3] = (int)pkbf(b.z, b.w);
  *(i32x4v*)(hbf + (size_t)i * 16) = w;
}

__global__ void khist(const int* __restrict__ src, int* __restrict__ cnt, int E) {
  int e = blockIdx.x * 256 + threadIdx.x;
  if (e < E) atomicAdd(&cnt[src[e]], 1);
}

__global__ void kscan1(const int* __restrict__ cnt, int* __restrict__ part,
                       int* __restrict__ bsums, int N) {
  __shared__ int sh[1024];
  int tid = threadIdx.x, i = blockIdx.x * 1024 + tid;
  int v = (i < N) ? cnt[i] : 0;
  sh[tid] = v; __syncthreads();
  for (int off = 1; off < 1024; off <<= 1) {
    int t = (tid >= off) ? sh[tid - off] : 0;
    __syncthreads();
    sh[tid] += t;
    __syncthreads();
  }
  if (i < N) part[i] = sh[tid] - v;
  if (tid == 1023) bsums[blockIdx.x] = sh[1023];
}

__global__ void kscan2(int* __restrict__ bsums, int nb) {
  __shared__ int sh[64];
  int tid = threadIdx.x;
  int v = (tid < nb) ? bsums[tid] : 0;
  sh[tid] = v; __syncthreads();
  for (int off = 1; off < 64; off <<= 1) {
    int t = (tid >= off) ? sh[tid - off] : 0;
    __syncthreads();
    sh[tid] += t;
    __syncthreads();
  }
  if (tid < nb) bsums[tid] = sh[tid] - v;
}

__global__ void kscan3(const int* __restrict__ bsums, int* __restrict__ part,
                       int* __restrict__ head, int N) {
  int i = blockIdx.x * 1024 + threadIdx.x;
  if (i < N) {
    int v = part[i] + bsums[blockIdx.x];
    part[i] = v;
    head[i] = v;
  }
}

// Scatter packed 32B edge records to sorted slots:
// word0=src word1=dst word2=pkbf(q^2,bpp) word3=pkbf(msa,chem) word4=pkbf(rel,cbm)
__global__ void kscatter(const int* __restrict__ src, const int* __restrict__ dst,
                         const float* __restrict__ dist, const float* __restrict__ bpp,
                         const float* __restrict__ msa, const float* __restrict__ chem,
                         const float* __restrict__ rel, const float* __restrict__ cbm,
                         int* __restrict__ head, int* __restrict__ rec, int E) {
  int e = blockIdx.x * 256 + threadIdx.x;
  if (e >= E) return;
  int s = src[e];
  int p = atomicAdd(&head[s], 1);
  float q = dist[e];
  i32x4v a;
  a[0] = s;
  a[1] = dst[e];
  a[2] = (int)pkbf(q * q, bpp[e]);
  a[3] = (int)pkbf(msa[e], chem[e]);
  *(i32x4v*)(rec + (size_t)p * 8) = a;
  rec[(size_t)p * 8 + 4] = (int)pkbf(rel[e], cbm[e]);
}

// Edge layer1: t1 = silu(feat . W1 + b1). 68.5 KB LDS -> 2 blocks/CU,
// 4 waves/SIMD. Record prefetched one tile ahead (no serial indirection).
__global__ __launch_bounds__(512, 4)
void kedgeA(const char* __restrict__ hbf, const int* __restrict__ rec,
            const float* __restrict__ mW1, const float* __restrict__ mb1,
            char* __restrict__ t1, int E)
{
  __shared__ short wA0[16384], wA1[16384];   // 64 KB
  __shared__ short wE[2048];                  // 4 KB
  __shared__ float sb1[128];

  const int tid = threadIdx.x, wid = tid >> 6, lane = tid & 63;
  const int col = lane & 31, hi = lane >> 5;

  stage_w128t<512>(mW1, wA0, tid);
  stage_w128t<512>(mW1 + 16384, wA1, tid);
  for (int p = tid; p < 2048; p += 512) {
    int j = p >> 4, kk = p & 15;
    float w = (kk < 6) ? mW1[(256 + kk) * 128 + j] : 0.f;
    wE[j * 16 + kk] = (short)(pkbf(w, 0.f) & 0xffffu);
  }
  if (tid < 128) sb1[tid] = mb1[tid];
  __syncthreads();

  const int T = (E + 31) / 32;
  const int stride = gridDim.x * 8;
  int t = blockIdx.x * 8 + wid;
  if (t >= T) return;

  int p = t * 32 + col;
  int pc = p < E ? p : E - 1;
  i32x4v ra = *(const i32x4v*)(rec + (size_t)pc * 8);
  int ev2 = rec[(size_t)pc * 8 + 4];

  while (t < T) {
    bool va = p < E;
    int s = ra[0], d = ra[1];

    i32x4v b[8];
    #pragma unroll
    for (int kc = 0; kc < 8; ++kc)
      b[kc] = *(const i32x4v*)(hbf + (size_t)s * 256 + kc * 32 + hi * 16);

    // prefetch next tile's record (independent of this tile's chain)
    int tn = t + stride;
    int pn = tn * 32 + col;
    int pcn = pn < E ? pn : E - 1;
    i32x4v nra = *(const i32x4v*)(rec + (size_t)pcn * 8);
    int nev2 = rec[(size_t)pcn * 8 + 4];

    f32x16 acc[4];
    zacc4(acc);
    // GEMM1a (h_src . W1a), interleaving dst-row loads into freed chunks
    #pragma unroll
    for (int kc = 0; kc < 8; ++kc) {
      bf16x8 bb = __builtin_bit_cast(bf16x8, b[kc]);
      b[kc] = *(const i32x4v*)(hbf + (size_t)d * 256 + kc * 32 + hi * 16);
      #pragma unroll
      for (int jm = 0; jm < 4; ++jm)
        acc[jm] = MFMA32(ldsA(wA0, jm * 32 + col, kc * 16 + hi * 8), bb, acc[jm]);
    }
    // GEMM1b (h_dst . W1b)
    #pragma unroll
    for (int kc = 0; kc < 8; ++kc) {
      bf16x8 bb = __builtin_bit_cast(bf16x8, b[kc]);
      #pragma unroll
      for (int jm = 0; jm < 4; ++jm)
        acc[jm] = MFMA32(ldsA(wA1, jm * 32 + col, kc * 16 + hi * 8), bb, acc[jm]);
    }
    // extras (k 256..261 padded to 16)
    {
      i32x4v ev;
      ev[0] = hi ? 0 : ra[2];
      ev[1] = hi ? 0 : ra[3];
      ev[2] = hi ? 0 : ev2;
      ev[3] = 0;
      bf16x8 be = __builtin_bit_cast(bf16x8, ev);
      #pragma unroll
      for (int jm = 0; jm < 4; ++jm) {
        bf16x8 af = __builtin_bit_cast(bf16x8,
            *(const i32x4v*)((const char*)wE + (jm * 32 + col) * 32 + hi * 16));
        acc[jm] = MFMA32(af, be, acc[jm]);
      }
    }
    trans_store(acc, sb1, hi, t1 + (size_t)p * 256, va);

    t = tn; p = pn; ra = nra; ev2 = nev2;
  }
}

// Edge layer2 + c-layer: pure streaming over slots (no gathers).
// buf holds t1 on entry; m overwrites the same slots (per-wave read-before-
// write, so NOT __restrict__). 65.5 KB LDS -> 2 blocks/CU.
__global__ __launch_bounds__(512, 4)
void kedgeB(char* buf,
            const float* __restrict__ mW2, const float* __restrict__ mb2,
            const float* __restrict__ cW1, const float* __restrict__ cb1,
            const float* __restrict__ cW2v, const float* __restrict__ cb2,
            float* __restrict__ coef, int E)
{
  __shared__ short wA2[16384], wA3[16384];   // 64 KB
  __shared__ float sb2[128], scb1[128], scw2[128];
  __shared__ float scb2v[1];

  const int tid = threadIdx.x, wid = tid >> 6, lane = tid & 63;
  const int col = lane & 31, hi = lane >> 5;

  stage_w128t<512>(mW2, wA2, tid);
  stage_w128t<512>(cW1, wA3, tid);
  if (tid < 128) {
    sb2[tid] = mb2[tid]; scb1[tid] = cb1[tid]; scw2[tid] = cW2v[tid];
  }
  if (tid == 0) scb2v[0] = cb2[0];
  __syncthreads();

  const int T = (E + 31) / 32;
  const int stride = gridDim.x * 8;
  for (int t = blockIdx.x * 8 + wid; t < T; t += stride) {
    int p = t * 32 + col;
    bool va = p < E;
    int pc = va ? p : E - 1;

    i32x4v b[8];
    #pragma unroll
    for (int kc = 0; kc < 8; ++kc)
      b[kc] = *(const i32x4v*)(buf + (size_t)pc * 256 + kc * 32 + hi * 16);

    f32x16 acc[4];
    zacc4(acc);
    #pragma unroll
    for (int kc = 0; kc < 8; ++kc) {
      bf16x8 bb = __builtin_bit_cast(bf16x8, b[kc]);
      #pragma unroll
      for (int jm = 0; jm < 4; ++jm)
        acc[jm] = MFMA32(ldsA(wA2, jm * 32 + col, kc * 16 + hi * 8), bb, acc[jm]);
    }
    // m = silu(t2+b2): store over the same slot, b <- c-layer frags
    trans2s(acc, sb2, hi, b, buf + (size_t)p * 256, va);

    zacc4(acc);
    #pragma unroll
    for (int kc = 0; kc < 8; ++kc) {
      bf16x8 bb = __builtin_bit_cast(bf16x8, b[kc]);
      #pragma unroll
      for (int jm = 0; jm < 4; ++jm)
        acc[jm] = MFMA32(ldsA(wA3, jm * 32 + col, kc * 16 + hi * 8), bb, acc[jm]);
    }
    float part = 0.f;
    #pragma unroll
    for (int jm = 0; jm < 4; ++jm)
      #pragma unroll
      for (int r = 0; r < 16; ++r) {
        int rowloc = (r & 3) + 8 * (r >> 2) + 4 * hi;
        part += silu_f(acc[jm][r] + scb1[jm * 32 + rowloc]) * scw2[jm * 32 + rowloc];
      }
    part += __shfl_xor(part, 32);
    float cf = tanh_f(part + scb2v[0]);
    if (va && hi == 0) coef[p] = cf;
  }
}

// Streaming segmented sum over sorted slots: 16 threads per node.
__global__ __launch_bounds__(256)
void kagg(const char* __restrict__ m_ij, const int* __restrict__ row_start,
          const int* __restrict__ cnt, const float* __restrict__ coef,
          const int* __restrict__ rec, const float* __restrict__ x,
          char* __restrict__ mibf, float* __restrict__ outX, int N)
{
  int n = blockIdx.x * 16 + (threadIdx.x >> 4);
  int t = threadIdx.x & 15;
  if (n >= N) return;
  int st = row_start[n], c = cnt[n];
  float a[8] = {0.f, 0.f, 0.f, 0.f, 0.f, 0.f, 0.f, 0.f};
  for (int k = 0; k < c; ++k) {
    i32x4v u = *(const i32x4v*)(m_ij + (size_t)(st + k) * 256 + t * 16);
    #pragma unroll
    for (int q = 0; q < 4; ++q) {
      u32 w = (u32)u[q];
      a[q * 2]     += bf2f(w & 0xffffu);
      a[q * 2 + 1] += bf2f(w >> 16);
    }
  }
  float inv = 1.f / fmaxf((float)c, 1.f);
  i32x4v o;
  #pragma unroll
  for (int q = 0; q < 4; ++q) o[q] = (int)pkbf(a[q * 2] * inv, a[q * 2 + 1] * inv);
  *(i32x4v*)(mibf + (size_t)n * 256 + t * 16) = o;
  if (t == 0) {
    float x0 = x[(size_t)n * 3], x1 = x[(size_t)n * 3 + 1], x2 = x[(size_t)n * 3 + 2];
    float dx = 0.f, dy = 0.f, dz = 0.f;
    for (int k = 0; k < c; ++k) {
      float cf = coef[st + k];
      int dn = rec[(size_t)(st + k) * 8 + 1];
      dx += (x0 - x[(size_t)dn * 3])     * cf;
      dy += (x1 - x[(size_t)dn * 3 + 1]) * cf;
      dz += (x2 - x[(size_t)dn * 3 + 2]) * cf;
    }
    outX[(size_t)n * 3]     = x0 + dx * inv;
    outX[(size_t)n * 3 + 1] = x1 + dy * inv;
    outX[(size_t)n * 3 + 2] = x2 + dz * inv;
  }
}

// Node MLP layer1: t1h = silu([h | m_i] . hW1 + b1)
__global__ __launch_bounds__(512, 2)
void knode1(const char* __restrict__ hbf, const char* __restrict__ mibf,
            const float* __restrict__ hW1, const float* __restrict__ hb1,
            char* __restrict__ t1h, int N)
{
  __shared__ short wA0[16384], wA1[16384];
  __shared__ float sb1[128];
  const int tid = threadIdx.x, wid = tid >> 6, lane = tid & 63;
  const int col = lane & 31, hi = lane >> 5;
  stage_w128t<512>(hW1, wA0, tid);
  stage_w128t<512>(hW1 + 16384, wA1, tid);
  if (tid < 128) sb1[tid] = hb1[tid];
  __syncthreads();

  int T = (N + 31) / 32;
  int t = blockIdx.x * 8 + wid;
  if (t >= T) return;
  int n = t * 32 + col;
  bool va = n < N;
  int nc = va ? n : N - 1;

  i32x4v b[8];
  #pragma unroll
  for (int kc = 0; kc < 8; ++kc)
    b[kc] = *(const i32x4v*)(hbf + (size_t)nc * 256 + kc * 32 + hi * 16);

  f32x16 acc[4];
  zacc4(acc);
  #pragma unroll
  for (int kc = 0; kc < 8; ++kc) {
    bf16x8 bb = __builtin_bit_cast(bf16x8, b[kc]);
    b[kc] = *(const i32x4v*)(mibf + (size_t)nc * 256 + kc * 32 + hi * 16);
    #pragma unroll
    for (int jm = 0; jm < 4; ++jm)
      acc[jm] = MFMA32(ldsA(wA0, jm * 32 + col, kc * 16 + hi * 8), bb, acc[jm]);
  }
  #pragma unroll
  for (int kc = 0; kc < 8; ++kc) {
    bf16x8 bb = __builtin_bit_cast(bf16x8, b[kc]);
    #pragma unroll
    for (int jm = 0; jm < 4; ++jm)
      acc[jm] = MFMA32(ldsA(wA1, jm * 32 + col, kc * 16 + hi * 8), bb, acc[jm]);
  }
  trans_store(acc, sb1, hi, t1h + (size_t)n * 256, va);
}

// Node MLP layer2 + residual: h_out = h + t1h . hW2 + b2
__global__ __launch_bounds__(512, 2)
void knode2(const char* __restrict__ t1h, const float* __restrict__ hW2,
            const float* __restrict__ hb2, const float* __restrict__ h,
            float* __restrict__ outH, int N)
{
  __shared__ short wA0[16384];
  __shared__ float sb2[128];
  const int tid = threadIdx.x, wid = tid >> 6, lane = tid & 63;
  const int col = lane & 31, hi = lane >> 5;
  stage_w128t<512>(hW2, wA0, tid);
  if (tid < 128) sb2[tid] = hb2[tid];
  __syncthreads();

  int T = (N + 31) / 32;
  int t = blockIdx.x * 8 + wid;
  if (t >= T) return;
  int n = t * 32 + col;
  bool va = n < N;
  int nc = va ? n : N - 1;

  i32x4v b[8];
  #pragma unroll
  for (int kc = 0; kc < 8; ++kc)
    b[kc] = *(const i32x4v*)(t1h + (size_t)nc * 256 + kc * 32 + hi * 16);

  f32x16 acc[4];
  zacc4(acc);
  #pragma unroll
  for (int kc = 0; kc < 8; ++kc) {
    bf16x8 bb = __builtin_bit_cast(bf16x8, b[kc]);
    #pragma unroll
    for (int jm = 0; jm < 4; ++jm)
      acc[jm] = MFMA32(ldsA(wA0, jm * 32 + col, kc * 16 + hi * 8), bb, acc[jm]);
  }
  const float4* h4 = (const float4*)h;
  #pragma unroll
  for (int jm = 0; jm < 4; ++jm)
    #pragma unroll
    for (int rq = 0; rq < 4; ++rq) {
      int j0 = jm * 32 + rq * 8 + hi * 4;
      float4 hv = h4[(size_t)nc * 32 + (j0 >> 2)];
      float4 o;
      o.x = hv.x + acc[jm][rq * 4 + 0] + sb2[j0 + 0];
      o.y = hv.y + acc[jm][rq * 4 + 1] + sb2[j0 + 1];
      o.z = hv.z + acc[jm][rq * 4 + 2] + sb2[j0 + 2];
      o.w = hv.w + acc[jm][rq * 4 + 3] + sb2[j0 + 3];
      if (va) ((float4*)outH)[(size_t)nc * 32 + (j0 >> 2)] = o;
    }
}

// ===================== LAUNCH =====================

extern "C" void kernel_launch(void* const* d_in, const int* in_sizes, int n_in,
                              void* d_out, int out_size, void* d_ws, size_t ws_size,
                              hipStream_t stream) {
  const float* h    = (const float*)d_in[0];
  const float* x    = (const float*)d_in[1];
  const int*   src  = (const int*)d_in[2];
  const int*   dst  = (const int*)d_in[3];
  const float* dist = (const float*)d_in[4];
  const float* bpp  = (const float*)d_in[5];
  const float* msa  = (const float*)d_in[6];
  const float* chem = (const float*)d_in[7];
  const float* rel  = (const float*)d_in[8];
  const float* cbm  = (const float*)d_in[9];
  const float* mW1  = (const float*)d_in[10];
  const float* mb1  = (const float*)d_in[11];
  const float* mW2  = (const float*)d_in[12];
  const float* mb2  = (const float*)d_in[13];
  const float* hW1  = (const float*)d_in[14];
  const float* hb1  = (const float*)d_in[15];
  const float* hW2  = (const float*)d_in[16];
  const float* hb2  = (const float*)d_in[17];
  const float* cW1  = (const float*)d_in[18];
  const float* cb1  = (const float*)d_in[19];
  const float* cW2  = (const float*)d_in[20];
  const float* cb2  = (const float*)d_in[21];

  int N = in_sizes[0] / 128;
  int E = in_sizes[2];

  size_t off = 0;
  auto A = [&](size_t b) { size_t o = off; off += (b + 255) & ~(size_t)255; return o; };
  size_t o_cnt  = A((size_t)N * 4);
  size_t o_rs   = A((size_t)N * 4);
  size_t o_head = A((size_t)N * 4);
  size_t o_rec  = A((size_t)E * 32);
  size_t o_coef = A((size_t)E * 4);
  size_t o_bs   = A(1024);
  size_t o_hbf  = A((size_t)N * 256);
  size_t o_mibf = A((size_t)N * 256);
  size_t o_big  = A((size_t)E * 256);   // t1 -> m_ij (in-place) -> t1h

  char* W = (char*)d_ws;
  int*   cnt32 = (int*)(W + o_cnt);
  int*   rs    = (int*)(W + o_rs);
  int*   head  = (int*)(W + o_head);
  int*   rec   = (int*)(W + o_rec);
  float* coef  = (float*)(W + o_coef);
  int*   bsums = (int*)(W + o_bs);
  char*  hbf   = W + o_hbf;
  char*  mibf  = W + o_mibf;
  char*  big   = W + o_big;

  hipMemsetAsync(cnt32, 0, (size_t)N * 4, stream);
  kconv<<<(N * 16 + 255) / 256, 256, 0, stream>>>(h, hbf, N * 16);
  khist<<<(E + 255) / 256, 256, 0, stream>>>(src, cnt32, E);
  int nb = (N + 1023) / 1024;
  kscan1<<<nb, 1024, 0, stream>>>(cnt32, rs, bsums, N);
  kscan2<<<1, 64, 0, stream>>>(bsums, nb);
  kscan3<<<nb, 1024, 0, stream>>>(bsums, rs, head, N);
  kscatter<<<(E + 255) / 256, 256, 0, stream>>>(src, dst, dist, bpp, msa, chem, rel, cbm,
                                                head, rec, E);
  kedgeA<<<512, 512, 0, stream>>>(hbf, rec, mW1, mb1, big, E);
  kedgeB<<<512, 512, 0, stream>>>(big, mW2, mb2, cW1, cb1, cW2, cb2, coef, E);
  kagg<<<(N + 15) / 16, 256, 0, stream>>>(big, rs, cnt32, coef, rec, x,
                                          mibf, (float*)d_out + (size_t)N * 128, N);
  int tb = ((N + 31) / 32 + 7) / 8;
  knode1<<<tb, 512, 0, stream>>>(hbf, mibf, hW1, hb1, big, N);
  knode2<<<tb, 512, 0, stream>>>(big, hW2, hb2, h, (float*)d_out, N);
}

// Round 7
// 722.449 us; speedup vs baseline: 1.6154x; 1.3644x over previous
//
#include <hip/hip_runtime.h>
#include <hip/hip_bf16.h>

typedef short bf16x8 __attribute__((ext_vector_type(8)));
typedef float f32x16 __attribute__((ext_vector_type(16)));
typedef int   i32x4v __attribute__((ext_vector_type(4)));
typedef unsigned u32;

#define MFMA32(a,b,c) __builtin_amdgcn_mfma_f32_32x32x16_bf16((a),(b),(c),0,0,0)

__device__ __forceinline__ u32 pkbf(float x, float y) {
  union { u32 u; __hip_bfloat16 h[2]; } t;
  t.h[0] = __float2bfloat16(x);
  t.h[1] = __float2bfloat16(y);
  return t.u;
}
__device__ __forceinline__ float bf2f(u32 lo16) {
  union { u32 u; float f; } t; t.u = lo16 << 16; return t.f;
}
__device__ __forceinline__ float silu_f(float v) { return v / (1.f + __expf(-v)); }
__device__ __forceinline__ float tanh_f(float v) {
  float e = __expf(2.f * fabsf(v));
  float t = 1.f - 2.f / (e + 1.f);
  return copysignf(t, v);
}

// Stage [128][128] f32 weight block (row k = in, col j = out) into LDS
// transposed bf16 wA[j][k] with 16B-unit XOR swizzle.
template<int NT>
__device__ __forceinline__ void stage_w128t(const float* __restrict__ W, short* wA, int tid) {
  for (int p = tid; p < 8192; p += NT) {
    int j = p & 127;
    int k = (p >> 7) << 1;
    u32 u = pkbf(W[k * 128 + j], W[k * 128 + 128 + j]);
    int off = j * 256 + (((k >> 3) ^ (j & 15)) << 4) + ((k & 7) << 1);
    *(u32*)((char*)wA + off) = u;
  }
}
__device__ __forceinline__ bf16x8 ldsA(const short* wA, int j, int kbase) {
  int off = j * 256 + (((kbase >> 3) ^ (j & 15)) << 4);
  return __builtin_bit_cast(bf16x8, *(const i32x4v*)((const char*)wA + off));
}

__device__ __forceinline__ void zacc4(f32x16 (&acc)[4]) {
  #pragma unroll
  for (int jm = 0; jm < 4; ++jm)
    #pragma unroll
    for (int r = 0; r < 16; ++r) acc[jm][r] = 0.f;
}

// Store one jm-block (32 dims) of a row as 2x16B contiguous chunks per lane,
// after a hi-pair exchange. Layout matches the kc*32+hi*16 B-fragment loads
// (proven by knode1->knode2 round trip since r2).
__device__ __forceinline__ void row_chunks(u32 p0, u32 p1, u32 p2, u32 p3,
                                           u32 p4, u32 p5, u32 p6, u32 p7,
                                           int hi, char* rowptr, int jm) {
  u32 x0 = (u32)__shfl_xor((int)(hi ? p0 : p4), 32);
  u32 x1 = (u32)__shfl_xor((int)(hi ? p1 : p5), 32);
  u32 x2 = (u32)__shfl_xor((int)(hi ? p2 : p6), 32);
  u32 x3 = (u32)__shfl_xor((int)(hi ? p3 : p7), 32);
  i32x4v c0, c1;
  if (hi) {
    c0[0] = (int)x0; c0[1] = (int)x1; c0[2] = (int)p4; c0[3] = (int)p5;
    c1[0] = (int)x2; c1[1] = (int)x3; c1[2] = (int)p6; c1[3] = (int)p7;
  } else {
    c0[0] = (int)p0; c0[1] = (int)p1; c0[2] = (int)x0; c0[3] = (int)x1;
    c1[0] = (int)p2; c1[1] = (int)p3; c1[2] = (int)x2; c1[3] = (int)x3;
  }
  *(i32x4v*)(rowptr + jm * 64 + hi * 32)      = c0;
  *(i32x4v*)(rowptr + jm * 64 + hi * 32 + 16) = c1;
}

// C-layout -> silu(+bias) -> row store ONLY (kedgeA epilogue).
__device__ __forceinline__ void trans_store(f32x16 (&acc)[4], const float* bias, int hi,
                                            char* rowptr, bool va) {
  #pragma unroll
  for (int jm = 0; jm < 4; ++jm) {
    float v[16];
    #pragma unroll
    for (int r = 0; r < 16; ++r) {
      int rowloc = (r & 3) + 8 * (r >> 2) + 4 * hi;
      v[r] = silu_f(acc[jm][r] + bias[jm * 32 + rowloc]);
    }
    u32 p0 = pkbf(v[0], v[1]),  p1 = pkbf(v[2], v[3]);
    u32 p2 = pkbf(v[4], v[5]),  p3 = pkbf(v[6], v[7]);
    u32 p4 = pkbf(v[8], v[9]),  p5 = pkbf(v[10], v[11]);
    u32 p6 = pkbf(v[12], v[13]), p7 = pkbf(v[14], v[15]);
    if (va) row_chunks(p0, p1, p2, p3, p4, p5, p6, p7, hi, rowptr, jm);
  }
}

// C-layout -> silu(+bias) -> bfr frags + row store (kedgeB, m store).
__device__ __forceinline__ void trans2s(f32x16 (&acc)[4], const float* bias, int hi,
                                        i32x4v (&bfr)[8], char* rowptr, bool va) {
  #pragma unroll
  for (int jm = 0; jm < 4; ++jm) {
    float v[16];
    #pragma unroll
    for (int r = 0; r < 16; ++r) {
      int rowloc = (r & 3) + 8 * (r >> 2) + 4 * hi;
      v[r] = silu_f(acc[jm][r] + bias[jm * 32 + rowloc]);
    }
    u32 p0 = pkbf(v[0], v[1]),  p1 = pkbf(v[2], v[3]);
    u32 p2 = pkbf(v[4], v[5]),  p3 = pkbf(v[6], v[7]);
    u32 p4 = pkbf(v[8], v[9]),  p5 = pkbf(v[10], v[11]);
    u32 p6 = pkbf(v[12], v[13]), p7 = pkbf(v[14], v[15]);
    {
      u32 g1 = (u32)__shfl_xor((int)(hi ? p0 : p2), 32);
      u32 g2 = (u32)__shfl_xor((int)(hi ? p1 : p3), 32);
      i32x4v w;
      w[0] = hi ? (int)g1 : (int)p0;
      w[1] = hi ? (int)g2 : (int)p1;
      w[2] = hi ? (int)p2 : (int)g1;
      w[3] = hi ? (int)p3 : (int)g2;
      bfr[jm * 2] = w;
      u32 g1b = (u32)__shfl_xor((int)(hi ? p4 : p6), 32);
      u32 g2b = (u32)__shfl_xor((int)(hi ? p5 : p7), 32);
      i32x4v w2;
      w2[0] = hi ? (int)g1b : (int)p4;
      w2[1] = hi ? (int)g2b : (int)p5;
      w2[2] = hi ? (int)p6 : (int)g1b;
      w2[3] = hi ? (int)p7 : (int)g2b;
      bfr[jm * 2 + 1] = w2;
    }
    if (va) row_chunks(p0, p1, p2, p3, p4, p5, p6, p7, hi, rowptr, jm);
  }
}

// ===================== PIPELINE =====================

__global__ void kconv(const float* __restrict__ h, char* __restrict__ hbf, int total16) {
  int i = blockIdx.x * 256 + threadIdx.x;
  if (i >= total16) return;
  const float4* h4 = (const float4*)h;
  float4 a = h4[(size_t)i * 2], b = h4[(size_t)i * 2 + 1];
  i32x4v w;
  w[0] = (int)pkbf(a.x, a.y); w[1] = (int)pkbf(a.z, a.w);
  w[2] = (int)pkbf(b.x, b.y); w[3] = (int)pkbf(b.z, b.w);
  *(i32x4v*)(hbf + (size_t)i * 16) = w;
}

__global__ void khist(const int* __restrict__ src, int* __restrict__ cnt, int E) {
  int e = blockIdx.x * 256 + threadIdx.x;
  if (e < E) atomicAdd(&cnt[src[e]], 1);
}

__global__ void kscan1(const int* __restrict__ cnt, int* __restrict__ part,
                       int* __restrict__ bsums, int N) {
  __shared__ int sh[1024];
  int tid = threadIdx.x, i = blockIdx.x * 1024 + tid;
  int v = (i < N) ? cnt[i] : 0;
  sh[tid] = v; __syncthreads();
  for (int off = 1; off < 1024; off <<= 1) {
    int t = (tid >= off) ? sh[tid - off] : 0;
    __syncthreads();
    sh[tid] += t;
    __syncthreads();
  }
  if (i < N) part[i] = sh[tid] - v;
  if (tid == 1023) bsums[blockIdx.x] = sh[1023];
}

__global__ void kscan2(int* __restrict__ bsums, int nb) {
  __shared__ int sh[64];
  int tid = threadIdx.x;
  int v = (tid < nb) ? bsums[tid] : 0;
  sh[tid] = v; __syncthreads();
  for (int off = 1; off < 64; off <<= 1) {
    int t = (tid >= off) ? sh[tid - off] : 0;
    __syncthreads();
    sh[tid] += t;
    __syncthreads();
  }
  if (tid < nb) bsums[tid] = sh[tid] - v;
}

__global__ void kscan3(const int* __restrict__ bsums, int* __restrict__ part,
                       int* __restrict__ head, int N) {
  int i = blockIdx.x * 1024 + threadIdx.x;
  if (i < N) {
    int v = part[i] + bsums[blockIdx.x];
    part[i] = v;
    head[i] = v;
  }
}

// Scatter packed 32B edge records to sorted slots:
// word0=src word1=dst word2=pkbf(q^2,bpp) word3=pkbf(msa,chem) word4=pkbf(rel,cbm)
__global__ void kscatter(const int* __restrict__ src, const int* __restrict__ dst,
                         const float* __restrict__ dist, const float* __restrict__ bpp,
                         const float* __restrict__ msa, const float* __restrict__ chem,
                         const float* __restrict__ rel, const float* __restrict__ cbm,
                         int* __restrict__ head, int* __restrict__ rec, int E) {
  int e = blockIdx.x * 256 + threadIdx.x;
  if (e >= E) return;
  int s = src[e];
  int p = atomicAdd(&head[s], 1);
  float q = dist[e];
  i32x4v a;
  a[0] = s;
  a[1] = dst[e];
  a[2] = (int)pkbf(q * q, bpp[e]);
  a[3] = (int)pkbf(msa[e], chem[e]);
  *(i32x4v*)(rec + (size_t)p * 8) = a;
  rec[(size_t)p * 8 + 4] = (int)pkbf(rel[e], cbm[e]);
}

// Edge layer1: t1 = silu(feat . W1 + b1). 68.5 KB LDS -> 2 blocks/CU.
// (512,2): compiler picks 128 VGPRs for this body (r2/r5-proven) -> no spill;
// (512,4) snapped to 64 VGPRs and spilled (r6 post-mortem).
__global__ __launch_bounds__(512, 2)
void kedgeA(const char* __restrict__ hbf, const int* __restrict__ rec,
            const float* __restrict__ mW1, const float* __restrict__ mb1,
            char* __restrict__ t1, int E)
{
  __shared__ short wA0[16384], wA1[16384];   // 64 KB
  __shared__ short wE[2048];                  // 4 KB
  __shared__ float sb1[128];

  const int tid = threadIdx.x, wid = tid >> 6, lane = tid & 63;
  const int col = lane & 31, hi = lane >> 5;

  stage_w128t<512>(mW1, wA0, tid);
  stage_w128t<512>(mW1 + 16384, wA1, tid);
  for (int p = tid; p < 2048; p += 512) {
    int j = p >> 4, kk = p & 15;
    float w = (kk < 6) ? mW1[(256 + kk) * 128 + j] : 0.f;
    wE[j * 16 + kk] = (short)(pkbf(w, 0.f) & 0xffffu);
  }
  if (tid < 128) sb1[tid] = mb1[tid];
  __syncthreads();

  const int T = (E + 31) / 32;
  const int stride = gridDim.x * 8;
  int t = blockIdx.x * 8 + wid;
  if (t >= T) return;

  int p = t * 32 + col;
  int pc = p < E ? p : E - 1;
  i32x4v ra = *(const i32x4v*)(rec + (size_t)pc * 8);
  int ev2 = rec[(size_t)pc * 8 + 4];

  while (t < T) {
    bool va = p < E;
    int s = ra[0], d = ra[1];

    i32x4v b[8];
    #pragma unroll
    for (int kc = 0; kc < 8; ++kc)
      b[kc] = *(const i32x4v*)(hbf + (size_t)s * 256 + kc * 32 + hi * 16);

    // prefetch next tile's record (independent of this tile's chain)
    int tn = t + stride;
    int pn = tn * 32 + col;
    int pcn = pn < E ? pn : E - 1;
    i32x4v nra = *(const i32x4v*)(rec + (size_t)pcn * 8);
    int nev2 = rec[(size_t)pcn * 8 + 4];

    f32x16 acc[4];
    zacc4(acc);
    // GEMM1a (h_src . W1a), interleaving dst-row loads into freed chunks
    #pragma unroll
    for (int kc = 0; kc < 8; ++kc) {
      bf16x8 bb = __builtin_bit_cast(bf16x8, b[kc]);
      b[kc] = *(const i32x4v*)(hbf + (size_t)d * 256 + kc * 32 + hi * 16);
      #pragma unroll
      for (int jm = 0; jm < 4; ++jm)
        acc[jm] = MFMA32(ldsA(wA0, jm * 32 + col, kc * 16 + hi * 8), bb, acc[jm]);
    }
    // GEMM1b (h_dst . W1b)
    #pragma unroll
    for (int kc = 0; kc < 8; ++kc) {
      bf16x8 bb = __builtin_bit_cast(bf16x8, b[kc]);
      #pragma unroll
      for (int jm = 0; jm < 4; ++jm)
        acc[jm] = MFMA32(ldsA(wA1, jm * 32 + col, kc * 16 + hi * 8), bb, acc[jm]);
    }
    // extras (k 256..261 padded to 16)
    {
      i32x4v ev;
      ev[0] = hi ? 0 : ra[2];
      ev[1] = hi ? 0 : ra[3];
      ev[2] = hi ? 0 : ev2;
      ev[3] = 0;
      bf16x8 be = __builtin_bit_cast(bf16x8, ev);
      #pragma unroll
      for (int jm = 0; jm < 4; ++jm) {
        bf16x8 af = __builtin_bit_cast(bf16x8,
            *(const i32x4v*)((const char*)wE + (jm * 32 + col) * 32 + hi * 16));
        acc[jm] = MFMA32(af, be, acc[jm]);
      }
    }
    trans_store(acc, sb1, hi, t1 + (size_t)p * 256, va);

    t = tn; p = pn; ra = nra; ev2 = nev2;
  }
}

// Edge layer2 + c-layer: pure streaming over slots (no gathers).
// buf holds t1 on entry; m overwrites the same slots (per-wave read-before-
// write, so NOT __restrict__). 65.5 KB LDS -> 2 blocks/CU. (512,2) -> 128 VGPR.
__global__ __launch_bounds__(512, 2)
void kedgeB(char* buf,
            const float* __restrict__ mW2, const float* __restrict__ mb2,
            const float* __restrict__ cW1, const float* __restrict__ cb1,
            const float* __restrict__ cW2v, const float* __restrict__ cb2,
            float* __restrict__ coef, int E)
{
  __shared__ short wA2[16384], wA3[16384];   // 64 KB
  __shared__ float sb2[128], scb1[128], scw2[128];
  __shared__ float scb2v[1];

  const int tid = threadIdx.x, wid = tid >> 6, lane = tid & 63;
  const int col = lane & 31, hi = lane >> 5;

  stage_w128t<512>(mW2, wA2, tid);
  stage_w128t<512>(cW1, wA3, tid);
  if (tid < 128) {
    sb2[tid] = mb2[tid]; scb1[tid] = cb1[tid]; scw2[tid] = cW2v[tid];
  }
  if (tid == 0) scb2v[0] = cb2[0];
  __syncthreads();

  const int T = (E + 31) / 32;
  const int stride = gridDim.x * 8;
  for (int t = blockIdx.x * 8 + wid; t < T; t += stride) {
    int p = t * 32 + col;
    bool va = p < E;
    int pc = va ? p : E - 1;

    i32x4v b[8];
    #pragma unroll
    for (int kc = 0; kc < 8; ++kc)
      b[kc] = *(const i32x4v*)(buf + (size_t)pc * 256 + kc * 32 + hi * 16);

    f32x16 acc[4];
    zacc4(acc);
    #pragma unroll
    for (int kc = 0; kc < 8; ++kc) {
      bf16x8 bb = __builtin_bit_cast(bf16x8, b[kc]);
      #pragma unroll
      for (int jm = 0; jm < 4; ++jm)
        acc[jm] = MFMA32(ldsA(wA2, jm * 32 + col, kc * 16 + hi * 8), bb, acc[jm]);
    }
    // m = silu(t2+b2): store over the same slot, b <- c-layer frags
    trans2s(acc, sb2, hi, b, buf + (size_t)p * 256, va);

    zacc4(acc);
    #pragma unroll
    for (int kc = 0; kc < 8; ++kc) {
      bf16x8 bb = __builtin_bit_cast(bf16x8, b[kc]);
      #pragma unroll
      for (int jm = 0; jm < 4; ++jm)
        acc[jm] = MFMA32(ldsA(wA3, jm * 32 + col, kc * 16 + hi * 8), bb, acc[jm]);
    }
    float part = 0.f;
    #pragma unroll
    for (int jm = 0; jm < 4; ++jm)
      #pragma unroll
      for (int r = 0; r < 16; ++r) {
        int rowloc = (r & 3) + 8 * (r >> 2) + 4 * hi;
        part += silu_f(acc[jm][r] + scb1[jm * 32 + rowloc]) * scw2[jm * 32 + rowloc];
      }
    part += __shfl_xor(part, 32);
    float cf = tanh_f(part + scb2v[0]);
    if (va && hi == 0) coef[p] = cf;
  }
}

// Streaming segmented sum over sorted slots: 16 threads per node.
__global__ __launch_bounds__(256)
void kagg(const char* __restrict__ m_ij, const int* __restrict__ row_start,
          const int* __restrict__ cnt, const float* __restrict__ coef,
          const int* __restrict__ rec, const float* __restrict__ x,
          char* __restrict__ mibf, float* __restrict__ outX, int N)
{
  int n = blockIdx.x * 16 + (threadIdx.x >> 4);
  int t = threadIdx.x & 15;
  if (n >= N) return;
  int st = row_start[n], c = cnt[n];
  float a[8] = {0.f, 0.f, 0.f, 0.f, 0.f, 0.f, 0.f, 0.f};
  for (int k = 0; k < c; ++k) {
    i32x4v u = *(const i32x4v*)(m_ij + (size_t)(st + k) * 256 + t * 16);
    #pragma unroll
    for (int q = 0; q < 4; ++q) {
      u32 w = (u32)u[q];
      a[q * 2]     += bf2f(w & 0xffffu);
      a[q * 2 + 1] += bf2f(w >> 16);
    }
  }
  float inv = 1.f / fmaxf((float)c, 1.f);
  i32x4v o;
  #pragma unroll
  for (int q = 0; q < 4; ++q) o[q] = (int)pkbf(a[q * 2] * inv, a[q * 2 + 1] * inv);
  *(i32x4v*)(mibf + (size_t)n * 256 + t * 16) = o;
  if (t == 0) {
    float x0 = x[(size_t)n * 3], x1 = x[(size_t)n * 3 + 1], x2 = x[(size_t)n * 3 + 2];
    float dx = 0.f, dy = 0.f, dz = 0.f;
    for (int k = 0; k < c; ++k) {
      float cf = coef[st + k];
      int dn = rec[(size_t)(st + k) * 8 + 1];
      dx += (x0 - x[(size_t)dn * 3])     * cf;
      dy += (x1 - x[(size_t)dn * 3 + 1]) * cf;
      dz += (x2 - x[(size_t)dn * 3 + 2]) * cf;
    }
    outX[(size_t)n * 3]     = x0 + dx * inv;
    outX[(size_t)n * 3 + 1] = x1 + dy * inv;
    outX[(size_t)n * 3 + 2] = x2 + dz * inv;
  }
}

// Node MLP layer1: t1h = silu([h | m_i] . hW1 + b1)
__global__ __launch_bounds__(512, 2)
void knode1(const char* __restrict__ hbf, const char* __restrict__ mibf,
            const float* __restrict__ hW1, const float* __restrict__ hb1,
            char* __restrict__ t1h, int N)
{
  __shared__ short wA0[16384], wA1[16384];
  __shared__ float sb1[128];
  const int tid = threadIdx.x, wid = tid >> 6, lane = tid & 63;
  const int col = lane & 31, hi = lane >> 5;
  stage_w128t<512>(hW1, wA0, tid);
  stage_w128t<512>(hW1 + 16384, wA1, tid);
  if (tid < 128) sb1[tid] = hb1[tid];
  __syncthreads();

  int T = (N + 31) / 32;
  int t = blockIdx.x * 8 + wid;
  if (t >= T) return;
  int n = t * 32 + col;
  bool va = n < N;
  int nc = va ? n : N - 1;

  i32x4v b[8];
  #pragma unroll
  for (int kc = 0; kc < 8; ++kc)
    b[kc] = *(const i32x4v*)(hbf + (size_t)nc * 256 + kc * 32 + hi * 16);

  f32x16 acc[4];
  zacc4(acc);
  #pragma unroll
  for (int kc = 0; kc < 8; ++kc) {
    bf16x8 bb = __builtin_bit_cast(bf16x8, b[kc]);
    b[kc] = *(const i32x4v*)(mibf + (size_t)nc * 256 + kc * 32 + hi * 16);
    #pragma unroll
    for (int jm = 0; jm < 4; ++jm)
      acc[jm] = MFMA32(ldsA(wA0, jm * 32 + col, kc * 16 + hi * 8), bb, acc[jm]);
  }
  #pragma unroll
  for (int kc = 0; kc < 8; ++kc) {
    bf16x8 bb = __builtin_bit_cast(bf16x8, b[kc]);
    #pragma unroll
    for (int jm = 0; jm < 4; ++jm)
      acc[jm] = MFMA32(ldsA(wA1, jm * 32 + col, kc * 16 + hi * 8), bb, acc[jm]);
  }
  trans_store(acc, sb1, hi, t1h + (size_t)n * 256, va);
}

// Node MLP layer2 + residual: h_out = h + t1h . hW2 + b2
__global__ __launch_bounds__(512, 2)
void knode2(const char* __restrict__ t1h, const float* __restrict__ hW2,
            const float* __restrict__ hb2, const float* __restrict__ h,
            float* __restrict__ outH, int N)
{
  __shared__ short wA0[16384];
  __shared__ float sb2[128];
  const int tid = threadIdx.x, wid = tid >> 6, lane = tid & 63;
  const int col = lane & 31, hi = lane >> 5;
  stage_w128t<512>(hW2, wA0, tid);
  if (tid < 128) sb2[tid] = hb2[tid];
  __syncthreads();

  int T = (N + 31) / 32;
  int t = blockIdx.x * 8 + wid;
  if (t >= T) return;
  int n = t * 32 + col;
  bool va = n < N;
  int nc = va ? n : N - 1;

  i32x4v b[8];
  #pragma unroll
  for (int kc = 0; kc < 8; ++kc)
    b[kc] = *(const i32x4v*)(t1h + (size_t)nc * 256 + kc * 32 + hi * 16);

  f32x16 acc[4];
  zacc4(acc);
  #pragma unroll
  for (int kc = 0; kc < 8; ++kc) {
    bf16x8 bb = __builtin_bit_cast(bf16x8, b[kc]);
    #pragma unroll
    for (int jm = 0; jm < 4; ++jm)
      acc[jm] = MFMA32(ldsA(wA0, jm * 32 + col, kc * 16 + hi * 8), bb, acc[jm]);
  }
  const float4* h4 = (const float4*)h;
  #pragma unroll
  for (int jm = 0; jm < 4; ++jm)
    #pragma unroll
    for (int rq = 0; rq < 4; ++rq) {
      int j0 = jm * 32 + rq * 8 + hi * 4;
      float4 hv = h4[(size_t)nc * 32 + (j0 >> 2)];
      float4 o;
      o.x = hv.x + acc[jm][rq * 4 + 0] + sb2[j0 + 0];
      o.y = hv.y + acc[jm][rq * 4 + 1] + sb2[j0 + 1];
      o.z = hv.z + acc[jm][rq * 4 + 2] + sb2[j0 + 2];
      o.w = hv.w + acc[jm][rq * 4 + 3] + sb2[j0 + 3];
      if (va) ((float4*)outH)[(size_t)nc * 32 + (j0 >> 2)] = o;
    }
}

// ===================== LAUNCH =====================

extern "C" void kernel_launch(void* const* d_in, const int* in_sizes, int n_in,
                              void* d_out, int out_size, void* d_ws, size_t ws_size,
                              hipStream_t stream) {
  const float* h    = (const float*)d_in[0];
  const float* x    = (const float*)d_in[1];
  const int*   src  = (const int*)d_in[2];
  const int*   dst  = (const int*)d_in[3];
  const float* dist = (const float*)d_in[4];
  const float* bpp  = (const float*)d_in[5];
  const float* msa  = (const float*)d_in[6];
  const float* chem = (const float*)d_in[7];
  const float* rel  = (const float*)d_in[8];
  const float* cbm  = (const float*)d_in[9];
  const float* mW1  = (const float*)d_in[10];
  const float* mb1  = (const float*)d_in[11];
  const float* mW2  = (const float*)d_in[12];
  const float* mb2  = (const float*)d_in[13];
  const float* hW1  = (const float*)d_in[14];
  const float* hb1  = (const float*)d_in[15];
  const float* hW2  = (const float*)d_in[16];
  const float* hb2  = (const float*)d_in[17];
  const float* cW1  = (const float*)d_in[18];
  const float* cb1  = (const float*)d_in[19];
  const float* cW2  = (const float*)d_in[20];
  const float* cb2  = (const float*)d_in[21];

  int N = in_sizes[0] / 128;
  int E = in_sizes[2];

  size_t off = 0;
  auto A = [&](size_t b) { size_t o = off; off += (b + 255) & ~(size_t)255; return o; };
  size_t o_cnt  = A((size_t)N * 4);
  size_t o_rs   = A((size_t)N * 4);
  size_t o_head = A((size_t)N * 4);
  size_t o_rec  = A((size_t)E * 32);
  size_t o_coef = A((size_t)E * 4);
  size_t o_bs   = A(1024);
  size_t o_hbf  = A((size_t)N * 256);
  size_t o_mibf = A((size_t)N * 256);
  size_t o_big  = A((size_t)E * 256);   // t1 -> m_ij (in-place) -> t1h

  char* W = (char*)d_ws;
  int*   cnt32 = (int*)(W + o_cnt);
  int*   rs    = (int*)(W + o_rs);
  int*   head  = (int*)(W + o_head);
  int*   rec   = (int*)(W + o_rec);
  float* coef  = (float*)(W + o_coef);
  int*   bsums = (int*)(W + o_bs);
  char*  hbf   = W + o_hbf;
  char*  mibf  = W + o_mibf;
  char*  big   = W + o_big;

  hipMemsetAsync(cnt32, 0, (size_t)N * 4, stream);
  kconv<<<(N * 16 + 255) / 256, 256, 0, stream>>>(h, hbf, N * 16);
  khist<<<(E + 255) / 256, 256, 0, stream>>>(src, cnt32, E);
  int nb = (N + 1023) / 1024;
  kscan1<<<nb, 1024, 0, stream>>>(cnt32, rs, bsums, N);
  kscan2<<<1, 64, 0, stream>>>(bsums, nb);
  kscan3<<<nb, 1024, 0, stream>>>(bsums, rs, head, N);
  kscatter<<<(E + 255) / 256, 256, 0, stream>>>(src, dst, dist, bpp, msa, chem, rel, cbm,
                                                head, rec, E);
  kedgeA<<<512, 512, 0, stream>>>(hbf, rec, mW1, mb1, big, E);
  kedgeB<<<512, 512, 0, stream>>>(big, mW2, mb2, cW1, cb1, cW2, cb2, coef, E);
  kagg<<<(N + 15) / 16, 256, 0, stream>>>(big, rs, cnt32, coef, rec, x,
                                          mibf, (float*)d_out + (size_t)N * 128, N);
  int tb = ((N + 31) / 32 + 7) / 8;
  knode1<<<tb, 512, 0, stream>>>(hbf, mibf, hW1, hb1, big, N);
  knode2<<<tb, 512, 0, stream>>>(big, hW2, hb2, h, (float*)d_out, N);
}

// Round 8
// 669.496 us; speedup vs baseline: 1.7432x; 1.0791x over previous
//
#include <hip/hip_runtime.h>
#include <hip/hip_bf16.h>

typedef short bf16x8 __attribute__((ext_vector_type(8)));
typedef float f32x16 __attribute__((ext_vector_type(16)));
typedef int   i32x4v __attribute__((ext_vector_type(4)));
typedef unsigned u32;

#define MFMA32(a,b,c) __builtin_amdgcn_mfma_f32_32x32x16_bf16((a),(b),(c),0,0,0)

__device__ __forceinline__ u32 pkbf(float x, float y) {
  union { u32 u; __hip_bfloat16 h[2]; } t;
  t.h[0] = __float2bfloat16(x);
  t.h[1] = __float2bfloat16(y);
  return t.u;
}
__device__ __forceinline__ float bf2f(u32 lo16) {
  union { u32 u; float f; } t; t.u = lo16 << 16; return t.f;
}
__device__ __forceinline__ float silu_f(float v) { return v / (1.f + __expf(-v)); }
__device__ __forceinline__ float tanh_f(float v) {
  float e = __expf(2.f * fabsf(v));
  float t = 1.f - 2.f / (e + 1.f);
  return copysignf(t, v);
}

// Stage [128][128] f32 weight block (row k = in, col j = out) into LDS
// transposed bf16 wA[j][k] with 16B-unit XOR swizzle.
template<int NT>
__device__ __forceinline__ void stage_w128t(const float* __restrict__ W, short* wA, int tid) {
  for (int p = tid; p < 8192; p += NT) {
    int j = p & 127;
    int k = (p >> 7) << 1;
    u32 u = pkbf(W[k * 128 + j], W[k * 128 + 128 + j]);
    int off = j * 256 + (((k >> 3) ^ (j & 15)) << 4) + ((k & 7) << 1);
    *(u32*)((char*)wA + off) = u;
  }
}
__device__ __forceinline__ bf16x8 ldsA(const short* wA, int j, int kbase) {
  int off = j * 256 + (((kbase >> 3) ^ (j & 15)) << 4);
  return __builtin_bit_cast(bf16x8, *(const i32x4v*)((const char*)wA + off));
}

// Store one jm-block (32 dims) of a row as 2x16B contiguous chunks per lane,
// after a hi-pair exchange. Layout matches the kc*32+hi*16 B-fragment loads.
__device__ __forceinline__ void row_chunks(u32 p0, u32 p1, u32 p2, u32 p3,
                                           u32 p4, u32 p5, u32 p6, u32 p7,
                                           int hi, char* rowptr, int jm) {
  u32 x0 = (u32)__shfl_xor((int)(hi ? p0 : p4), 32);
  u32 x1 = (u32)__shfl_xor((int)(hi ? p1 : p5), 32);
  u32 x2 = (u32)__shfl_xor((int)(hi ? p2 : p6), 32);
  u32 x3 = (u32)__shfl_xor((int)(hi ? p3 : p7), 32);
  i32x4v c0, c1;
  if (hi) {
    c0[0] = (int)x0; c0[1] = (int)x1; c0[2] = (int)p4; c0[3] = (int)p5;
    c1[0] = (int)x2; c1[1] = (int)x3; c1[2] = (int)p6; c1[3] = (int)p7;
  } else {
    c0[0] = (int)p0; c0[1] = (int)p1; c0[2] = (int)x0; c0[3] = (int)x1;
    c1[0] = (int)p2; c1[1] = (int)p3; c1[2] = (int)x2; c1[3] = (int)x3;
  }
  *(i32x4v*)(rowptr + jm * 64 + hi * 32)      = c0;
  *(i32x4v*)(rowptr + jm * 64 + hi * 32 + 16) = c1;
}

// One jm (global index) of C-layout -> silu(+bias) -> row store.
__device__ __forceinline__ void trans_store1(const f32x16& a, const float* bias, int hi,
                                             char* rowptr, bool va, int jm) {
  float v[16];
  #pragma unroll
  for (int r = 0; r < 16; ++r) {
    int rowloc = (r & 3) + 8 * (r >> 2) + 4 * hi;
    v[r] = silu_f(a[r] + bias[jm * 32 + rowloc]);
  }
  u32 p0 = pkbf(v[0], v[1]),  p1 = pkbf(v[2], v[3]);
  u32 p2 = pkbf(v[4], v[5]),  p3 = pkbf(v[6], v[7]);
  u32 p4 = pkbf(v[8], v[9]),  p5 = pkbf(v[10], v[11]);
  u32 p6 = pkbf(v[12], v[13]), p7 = pkbf(v[14], v[15]);
  if (va) row_chunks(p0, p1, p2, p3, p4, p5, p6, p7, hi, rowptr, jm);
}

// One jm: C-layout -> silu(+bias) -> B-frags (fr[jm*2], fr[jm*2+1]) + row store.
__device__ __forceinline__ void trans_frag1(const f32x16& a, const float* bias, int hi,
                                            i32x4v* fr, char* rowptr, bool va, int jm) {
  float v[16];
  #pragma unroll
  for (int r = 0; r < 16; ++r) {
    int rowloc = (r & 3) + 8 * (r >> 2) + 4 * hi;
    v[r] = silu_f(a[r] + bias[jm * 32 + rowloc]);
  }
  u32 p0 = pkbf(v[0], v[1]),  p1 = pkbf(v[2], v[3]);
  u32 p2 = pkbf(v[4], v[5]),  p3 = pkbf(v[6], v[7]);
  u32 p4 = pkbf(v[8], v[9]),  p5 = pkbf(v[10], v[11]);
  u32 p6 = pkbf(v[12], v[13]), p7 = pkbf(v[14], v[15]);
  {
    u32 g1 = (u32)__shfl_xor((int)(hi ? p0 : p2), 32);
    u32 g2 = (u32)__shfl_xor((int)(hi ? p1 : p3), 32);
    i32x4v w;
    w[0] = hi ? (int)g1 : (int)p0;
    w[1] = hi ? (int)g2 : (int)p1;
    w[2] = hi ? (int)p2 : (int)g1;
    w[3] = hi ? (int)p3 : (int)g2;
    fr[jm * 2] = w;
    u32 g1b = (u32)__shfl_xor((int)(hi ? p4 : p6), 32);
    u32 g2b = (u32)__shfl_xor((int)(hi ? p5 : p7), 32);
    i32x4v w2;
    w2[0] = hi ? (int)g1b : (int)p4;
    w2[1] = hi ? (int)g2b : (int)p5;
    w2[2] = hi ? (int)p6 : (int)g1b;
    w2[3] = hi ? (int)p7 : (int)g2b;
    fr[jm * 2 + 1] = w2;
  }
  if (va) row_chunks(p0, p1, p2, p3, p4, p5, p6, p7, hi, rowptr, jm);
}

// ===================== PIPELINE =====================

__global__ void kconv(const float* __restrict__ h, char* __restrict__ hbf, int total16) {
  int i = blockIdx.x * 256 + threadIdx.x;
  if (i >= total16) return;
  const float4* h4 = (const float4*)h;
  float4 a = h4[(size_t)i * 2], b = h4[(size_t)i * 2 + 1];
  i32x4v w;
  w[0] = (int)pkbf(a.x, a.y); w[1] = (int)pkbf(a.z, a.w);
  w[2] = (int)pkbf(b.x, b.y); w[3] = (int)pkbf(b.z, b.w);
  *(i32x4v*)(hbf + (size_t)i * 16) = w;
}

__global__ void khist(const int* __restrict__ src, int* __restrict__ cnt, int E) {
  int e = blockIdx.x * 256 + threadIdx.x;
  if (e < E) atomicAdd(&cnt[src[e]], 1);
}

__global__ void kscan1(const int* __restrict__ cnt, int* __restrict__ part,
                       int* __restrict__ bsums, int N) {
  __shared__ int sh[1024];
  int tid = threadIdx.x, i = blockIdx.x * 1024 + tid;
  int v = (i < N) ? cnt[i] : 0;
  sh[tid] = v; __syncthreads();
  for (int off = 1; off < 1024; off <<= 1) {
    int t = (tid >= off) ? sh[tid - off] : 0;
    __syncthreads();
    sh[tid] += t;
    __syncthreads();
  }
  if (i < N) part[i] = sh[tid] - v;
  if (tid == 1023) bsums[blockIdx.x] = sh[1023];
}

__global__ void kscan2(int* __restrict__ bsums, int nb) {
  __shared__ int sh[64];
  int tid = threadIdx.x;
  int v = (tid < nb) ? bsums[tid] : 0;
  sh[tid] = v; __syncthreads();
  for (int off = 1; off < 64; off <<= 1) {
    int t = (tid >= off) ? sh[tid - off] : 0;
    __syncthreads();
    sh[tid] += t;
    __syncthreads();
  }
  if (tid < nb) bsums[tid] = sh[tid] - v;
}

__global__ void kscan3(const int* __restrict__ bsums, int* __restrict__ part,
                       int* __restrict__ head, int N) {
  int i = blockIdx.x * 1024 + threadIdx.x;
  if (i < N) {
    int v = part[i] + bsums[blockIdx.x];
    part[i] = v;
    head[i] = v;
  }
}

// Scatter packed 32B edge records to sorted slots.
__global__ void kscatter(const int* __restrict__ src, const int* __restrict__ dst,
                         const float* __restrict__ dist, const float* __restrict__ bpp,
                         const float* __restrict__ msa, const float* __restrict__ chem,
                         const float* __restrict__ rel, const float* __restrict__ cbm,
                         int* __restrict__ head, int* __restrict__ rec, int E) {
  int e = blockIdx.x * 256 + threadIdx.x;
  if (e >= E) return;
  int s = src[e];
  int p = atomicAdd(&head[s], 1);
  float q = dist[e];
  i32x4v a;
  a[0] = s;
  a[1] = dst[e];
  a[2] = (int)pkbf(q * q, bpp[e]);
  a[3] = (int)pkbf(msa[e], chem[e]);
  *(i32x4v*)(rec + (size_t)p * 8) = a;
  rec[(size_t)p * 8 + 4] = (int)pkbf(rel[e], cbm[e]);
}

// Edge layer1: t1 = silu(feat . W1 + b1). Two jm-group passes (acc2[2] = 32
// VGPRs) keep peak register demand ~110 <= 128 -> no scratch spill.
__global__ __launch_bounds__(512, 2)
void kedgeA(const char* __restrict__ hbf, const int* __restrict__ rec,
            const float* __restrict__ mW1, const float* __restrict__ mb1,
            char* __restrict__ t1, int E)
{
  __shared__ short wA0[16384], wA1[16384];   // 64 KB
  __shared__ short wE[2048];                  // 4 KB
  __shared__ float sb1[128];

  const int tid = threadIdx.x, wid = tid >> 6, lane = tid & 63;
  const int col = lane & 31, hi = lane >> 5;

  stage_w128t<512>(mW1, wA0, tid);
  stage_w128t<512>(mW1 + 16384, wA1, tid);
  for (int p = tid; p < 2048; p += 512) {
    int j = p >> 4, kk = p & 15;
    float w = (kk < 6) ? mW1[(256 + kk) * 128 + j] : 0.f;
    wE[j * 16 + kk] = (short)(pkbf(w, 0.f) & 0xffffu);
  }
  if (tid < 128) sb1[tid] = mb1[tid];
  __syncthreads();

  const int T = (E + 31) / 32;
  const int stride = gridDim.x * 8;
  int t = blockIdx.x * 8 + wid;
  if (t >= T) return;

  int p = t * 32 + col;
  int pc = p < E ? p : E - 1;
  i32x4v ra = *(const i32x4v*)(rec + (size_t)pc * 8);
  int ev2 = rec[(size_t)pc * 8 + 4];

  while (t < T) {
    bool va = p < E;
    int s = ra[0], d = ra[1];

    i32x4v bs[8], bd[8];
    #pragma unroll
    for (int kc = 0; kc < 8; ++kc)
      bs[kc] = *(const i32x4v*)(hbf + (size_t)s * 256 + kc * 32 + hi * 16);
    #pragma unroll
    for (int kc = 0; kc < 8; ++kc)
      bd[kc] = *(const i32x4v*)(hbf + (size_t)d * 256 + kc * 32 + hi * 16);

    // prefetch next tile's record (independent of this tile's chain)
    int tn = t + stride;
    int pn = tn * 32 + col;
    int pcn = pn < E ? pn : E - 1;
    i32x4v nra = *(const i32x4v*)(rec + (size_t)pcn * 8);
    int nev2 = rec[(size_t)pcn * 8 + 4];

    char* rowptr = t1 + (size_t)p * 256;
    #pragma unroll
    for (int g = 0; g < 2; ++g) {
      f32x16 acc2[2];
      #pragma unroll
      for (int j2 = 0; j2 < 2; ++j2)
        #pragma unroll
        for (int r = 0; r < 16; ++r) acc2[j2][r] = 0.f;

      #pragma unroll
      for (int kc = 0; kc < 8; ++kc) {
        bf16x8 bb = __builtin_bit_cast(bf16x8, bs[kc]);
        #pragma unroll
        for (int j2 = 0; j2 < 2; ++j2)
          acc2[j2] = MFMA32(ldsA(wA0, (g * 2 + j2) * 32 + col, kc * 16 + hi * 8), bb, acc2[j2]);
      }
      #pragma unroll
      for (int kc = 0; kc < 8; ++kc) {
        bf16x8 bb = __builtin_bit_cast(bf16x8, bd[kc]);
        #pragma unroll
        for (int j2 = 0; j2 < 2; ++j2)
          acc2[j2] = MFMA32(ldsA(wA1, (g * 2 + j2) * 32 + col, kc * 16 + hi * 8), bb, acc2[j2]);
      }
      {
        i32x4v ev;
        ev[0] = hi ? 0 : ra[2];
        ev[1] = hi ? 0 : ra[3];
        ev[2] = hi ? 0 : ev2;
        ev[3] = 0;
        bf16x8 be = __builtin_bit_cast(bf16x8, ev);
        #pragma unroll
        for (int j2 = 0; j2 < 2; ++j2) {
          bf16x8 af = __builtin_bit_cast(bf16x8,
              *(const i32x4v*)((const char*)wE + ((g * 2 + j2) * 32 + col) * 32 + hi * 16));
          acc2[j2] = MFMA32(af, be, acc2[j2]);
        }
      }
      #pragma unroll
      for (int j2 = 0; j2 < 2; ++j2)
        trans_store1(acc2[j2], sb1, hi, rowptr, va, g * 2 + j2);
    }

    t = tn; p = pn; ra = nra; ev2 = nev2;
  }
}

// Edge layer2 + c-layer: pure streaming over slots. Two jm-group passes.
// buf holds t1 on entry; m overwrites the same slots (per-wave RBW).
__global__ __launch_bounds__(512, 2)
void kedgeB(char* buf,
            const float* __restrict__ mW2, const float* __restrict__ mb2,
            const float* __restrict__ cW1, const float* __restrict__ cb1,
            const float* __restrict__ cW2v, const float* __restrict__ cb2,
            float* __restrict__ coef, int E)
{
  __shared__ short wA2[16384], wA3[16384];   // 64 KB
  __shared__ float sb2[128], scb1[128], scw2[128];
  __shared__ float scb2v[1];

  const int tid = threadIdx.x, wid = tid >> 6, lane = tid & 63;
  const int col = lane & 31, hi = lane >> 5;

  stage_w128t<512>(mW2, wA2, tid);
  stage_w128t<512>(cW1, wA3, tid);
  if (tid < 128) {
    sb2[tid] = mb2[tid]; scb1[tid] = cb1[tid]; scw2[tid] = cW2v[tid];
  }
  if (tid == 0) scb2v[0] = cb2[0];
  __syncthreads();

  const int T = (E + 31) / 32;
  const int stride = gridDim.x * 8;
  for (int t = blockIdx.x * 8 + wid; t < T; t += stride) {
    int p = t * 32 + col;
    bool va = p < E;
    int pc = va ? p : E - 1;

    i32x4v b[8];
    #pragma unroll
    for (int kc = 0; kc < 8; ++kc)
      b[kc] = *(const i32x4v*)(buf + (size_t)pc * 256 + kc * 32 + hi * 16);

    char* rowptr = buf + (size_t)p * 256;
    i32x4v fr[8];
    #pragma unroll
    for (int g = 0; g < 2; ++g) {
      f32x16 acc2[2];
      #pragma unroll
      for (int j2 = 0; j2 < 2; ++j2)
        #pragma unroll
        for (int r = 0; r < 16; ++r) acc2[j2][r] = 0.f;
      #pragma unroll
      for (int kc = 0; kc < 8; ++kc) {
        bf16x8 bb = __builtin_bit_cast(bf16x8, b[kc]);
        #pragma unroll
        for (int j2 = 0; j2 < 2; ++j2)
          acc2[j2] = MFMA32(ldsA(wA2, (g * 2 + j2) * 32 + col, kc * 16 + hi * 8), bb, acc2[j2]);
      }
      #pragma unroll
      for (int j2 = 0; j2 < 2; ++j2)
        trans_frag1(acc2[j2], sb2, hi, fr, rowptr, va, g * 2 + j2);
    }

    float part = 0.f;
    #pragma unroll
    for (int g = 0; g < 2; ++g) {
      f32x16 acc2[2];
      #pragma unroll
      for (int j2 = 0; j2 < 2; ++j2)
        #pragma unroll
        for (int r = 0; r < 16; ++r) acc2[j2][r] = 0.f;
      #pragma unroll
      for (int kc = 0; kc < 8; ++kc) {
        bf16x8 bb = __builtin_bit_cast(bf16x8, fr[kc]);
        #pragma unroll
        for (int j2 = 0; j2 < 2; ++j2)
          acc2[j2] = MFMA32(ldsA(wA3, (g * 2 + j2) * 32 + col, kc * 16 + hi * 8), bb, acc2[j2]);
      }
      #pragma unroll
      for (int j2 = 0; j2 < 2; ++j2) {
        int jm = g * 2 + j2;
        #pragma unroll
        for (int r = 0; r < 16; ++r) {
          int rowloc = (r & 3) + 8 * (r >> 2) + 4 * hi;
          part += silu_f(acc2[j2][r] + scb1[jm * 32 + rowloc]) * scw2[jm * 32 + rowloc];
        }
      }
    }
    part += __shfl_xor(part, 32);
    float cf = tanh_f(part + scb2v[0]);
    if (va && hi == 0) coef[p] = cf;
  }
}

// Streaming segmented sum over sorted slots: 16 threads per node.
__global__ __launch_bounds__(256)
void kagg(const char* __restrict__ m_ij, const int* __restrict__ row_start,
          const int* __restrict__ cnt, const float* __restrict__ coef,
          const int* __restrict__ rec, const float* __restrict__ x,
          char* __restrict__ mibf, float* __restrict__ outX, int N)
{
  int n = blockIdx.x * 16 + (threadIdx.x >> 4);
  int t = threadIdx.x & 15;
  if (n >= N) return;
  int st = row_start[n], c = cnt[n];
  float a[8] = {0.f, 0.f, 0.f, 0.f, 0.f, 0.f, 0.f, 0.f};
  for (int k = 0; k < c; ++k) {
    i32x4v u = *(const i32x4v*)(m_ij + (size_t)(st + k) * 256 + t * 16);
    #pragma unroll
    for (int q = 0; q < 4; ++q) {
      u32 w = (u32)u[q];
      a[q * 2]     += bf2f(w & 0xffffu);
      a[q * 2 + 1] += bf2f(w >> 16);
    }
  }
  float inv = 1.f / fmaxf((float)c, 1.f);
  i32x4v o;
  #pragma unroll
  for (int q = 0; q < 4; ++q) o[q] = (int)pkbf(a[q * 2] * inv, a[q * 2 + 1] * inv);
  *(i32x4v*)(mibf + (size_t)n * 256 + t * 16) = o;
  if (t == 0) {
    float x0 = x[(size_t)n * 3], x1 = x[(size_t)n * 3 + 1], x2 = x[(size_t)n * 3 + 2];
    float dx = 0.f, dy = 0.f, dz = 0.f;
    for (int k = 0; k < c; ++k) {
      float cf = coef[st + k];
      int dn = rec[(size_t)(st + k) * 8 + 1];
      dx += (x0 - x[(size_t)dn * 3])     * cf;
      dy += (x1 - x[(size_t)dn * 3 + 1]) * cf;
      dz += (x2 - x[(size_t)dn * 3 + 2]) * cf;
    }
    outX[(size_t)n * 3]     = x0 + dx * inv;
    outX[(size_t)n * 3 + 1] = x1 + dy * inv;
    outX[(size_t)n * 3 + 2] = x2 + dz * inv;
  }
}

// Node MLP layer1: t1h = silu([h | m_i] . hW1 + b1)
__global__ __launch_bounds__(512, 2)
void knode1(const char* __restrict__ hbf, const char* __restrict__ mibf,
            const float* __restrict__ hW1, const float* __restrict__ hb1,
            char* __restrict__ t1h, int N)
{
  __shared__ short wA0[16384], wA1[16384];
  __shared__ float sb1[128];
  const int tid = threadIdx.x, wid = tid >> 6, lane = tid & 63;
  const int col = lane & 31, hi = lane >> 5;
  stage_w128t<512>(hW1, wA0, tid);
  stage_w128t<512>(hW1 + 16384, wA1, tid);
  if (tid < 128) sb1[tid] = hb1[tid];
  __syncthreads();

  int T = (N + 31) / 32;
  int t = blockIdx.x * 8 + wid;
  if (t >= T) return;
  int n = t * 32 + col;
  bool va = n < N;
  int nc = va ? n : N - 1;

  i32x4v bh[8], bm[8];
  #pragma unroll
  for (int kc = 0; kc < 8; ++kc)
    bh[kc] = *(const i32x4v*)(hbf + (size_t)nc * 256 + kc * 32 + hi * 16);
  #pragma unroll
  for (int kc = 0; kc < 8; ++kc)
    bm[kc] = *(const i32x4v*)(mibf + (size_t)nc * 256 + kc * 32 + hi * 16);

  char* rowptr = t1h + (size_t)n * 256;
  #pragma unroll
  for (int g = 0; g < 2; ++g) {
    f32x16 acc2[2];
    #pragma unroll
    for (int j2 = 0; j2 < 2; ++j2)
      #pragma unroll
      for (int r = 0; r < 16; ++r) acc2[j2][r] = 0.f;
    #pragma unroll
    for (int kc = 0; kc < 8; ++kc) {
      bf16x8 bb = __builtin_bit_cast(bf16x8, bh[kc]);
      #pragma unroll
      for (int j2 = 0; j2 < 2; ++j2)
        acc2[j2] = MFMA32(ldsA(wA0, (g * 2 + j2) * 32 + col, kc * 16 + hi * 8), bb, acc2[j2]);
    }
    #pragma unroll
    for (int kc = 0; kc < 8; ++kc) {
      bf16x8 bb = __builtin_bit_cast(bf16x8, bm[kc]);
      #pragma unroll
      for (int j2 = 0; j2 < 2; ++j2)
        acc2[j2] = MFMA32(ldsA(wA1, (g * 2 + j2) * 32 + col, kc * 16 + hi * 8), bb, acc2[j2]);
    }
    #pragma unroll
    for (int j2 = 0; j2 < 2; ++j2)
      trans_store1(acc2[j2], sb1, hi, rowptr, va, g * 2 + j2);
  }
}

// Node MLP layer2 + residual: h_out = h + t1h . hW2 + b2
__global__ __launch_bounds__(512, 2)
void knode2(const char* __restrict__ t1h, const float* __restrict__ hW2,
            const float* __restrict__ hb2, const float* __restrict__ h,
            float* __restrict__ outH, int N)
{
  __shared__ short wA0[16384];
  __shared__ float sb2[128];
  const int tid = threadIdx.x, wid = tid >> 6, lane = tid & 63;
  const int col = lane & 31, hi = lane >> 5;
  stage_w128t<512>(hW2, wA0, tid);
  if (tid < 128) sb2[tid] = hb2[tid];
  __syncthreads();

  int T = (N + 31) / 32;
  int t = blockIdx.x * 8 + wid;
  if (t >= T) return;
  int n = t * 32 + col;
  bool va = n < N;
  int nc = va ? n : N - 1;

  i32x4v b[8];
  #pragma unroll
  for (int kc = 0; kc < 8; ++kc)
    b[kc] = *(const i32x4v*)(t1h + (size_t)nc * 256 + kc * 32 + hi * 16);

  const float4* h4 = (const float4*)h;
  #pragma unroll
  for (int g = 0; g < 2; ++g) {
    f32x16 acc2[2];
    #pragma unroll
    for (int j2 = 0; j2 < 2; ++j2)
      #pragma unroll
      for (int r = 0; r < 16; ++r) acc2[j2][r] = 0.f;
    #pragma unroll
    for (int kc = 0; kc < 8; ++kc) {
      bf16x8 bb = __builtin_bit_cast(bf16x8, b[kc]);
      #pragma unroll
      for (int j2 = 0; j2 < 2; ++j2)
        acc2[j2] = MFMA32(ldsA(wA0, (g * 2 + j2) * 32 + col, kc * 16 + hi * 8), bb, acc2[j2]);
    }
    #pragma unroll
    for (int j2 = 0; j2 < 2; ++j2) {
      int jm = g * 2 + j2;
      #pragma unroll
      for (int rq = 0; rq < 4; ++rq) {
        int j0 = jm * 32 + rq * 8 + hi * 4;
        float4 hv = h4[(size_t)nc * 32 + (j0 >> 2)];
        float4 o;
        o.x = hv.x + acc2[j2][rq * 4 + 0] + sb2[j0 + 0];
        o.y = hv.y + acc2[j2][rq * 4 + 1] + sb2[j0 + 1];
        o.z = hv.z + acc2[j2][rq * 4 + 2] + sb2[j0 + 2];
        o.w = hv.w + acc2[j2][rq * 4 + 3] + sb2[j0 + 3];
        if (va) ((float4*)outH)[(size_t)nc * 32 + (j0 >> 2)] = o;
      }
    }
  }
}

// ===================== LAUNCH =====================

extern "C" void kernel_launch(void* const* d_in, const int* in_sizes, int n_in,
                              void* d_out, int out_size, void* d_ws, size_t ws_size,
                              hipStream_t stream) {
  const float* h    = (const float*)d_in[0];
  const float* x    = (const float*)d_in[1];
  const int*   src  = (const int*)d_in[2];
  const int*   dst  = (const int*)d_in[3];
  const float* dist = (const float*)d_in[4];
  const float* bpp  = (const float*)d_in[5];
  const float* msa  = (const float*)d_in[6];
  const float* chem = (const float*)d_in[7];
  const float* rel  = (const float*)d_in[8];
  const float* cbm  = (const float*)d_in[9];
  const float* mW1  = (const float*)d_in[10];
  const float* mb1  = (const float*)d_in[11];
  const float* mW2  = (const float*)d_in[12];
  const float* mb2  = (const float*)d_in[13];
  const float* hW1  = (const float*)d_in[14];
  const float* hb1  = (const float*)d_in[15];
  const float* hW2  = (const float*)d_in[16];
  const float* hb2  = (const float*)d_in[17];
  const float* cW1  = (const float*)d_in[18];
  const float* cb1  = (const float*)d_in[19];
  const float* cW2  = (const float*)d_in[20];
  const float* cb2  = (const float*)d_in[21];

  int N = in_sizes[0] / 128;
  int E = in_sizes[2];

  size_t off = 0;
  auto A = [&](size_t b) { size_t o = off; off += (b + 255) & ~(size_t)255; return o; };
  size_t o_cnt  = A((size_t)N * 4);
  size_t o_rs   = A((size_t)N * 4);
  size_t o_head = A((size_t)N * 4);
  size_t o_rec  = A((size_t)E * 32);
  size_t o_coef = A((size_t)E * 4);
  size_t o_bs   = A(1024);
  size_t o_hbf  = A((size_t)N * 256);
  size_t o_mibf = A((size_t)N * 256);
  size_t o_big  = A((size_t)E * 256);   // t1 -> m_ij (in-place) -> t1h

  char* W = (char*)d_ws;
  int*   cnt32 = (int*)(W + o_cnt);
  int*   rs    = (int*)(W + o_rs);
  int*   head  = (int*)(W + o_head);
  int*   rec   = (int*)(W + o_rec);
  float* coef  = (float*)(W + o_coef);
  int*   bsums = (int*)(W + o_bs);
  char*  hbf   = W + o_hbf;
  char*  mibf  = W + o_mibf;
  char*  big   = W + o_big;

  hipMemsetAsync(cnt32, 0, (size_t)N * 4, stream);
  kconv<<<(N * 16 + 255) / 256, 256, 0, stream>>>(h, hbf, N * 16);
  khist<<<(E + 255) / 256, 256, 0, stream>>>(src, cnt32, E);
  int nb = (N + 1023) / 1024;
  kscan1<<<nb, 1024, 0, stream>>>(cnt32, rs, bsums, N);
  kscan2<<<1, 64, 0, stream>>>(bsums, nb);
  kscan3<<<nb, 1024, 0, stream>>>(bsums, rs, head, N);
  kscatter<<<(E + 255) / 256, 256, 0, stream>>>(src, dst, dist, bpp, msa, chem, rel, cbm,
                                                head, rec, E);
  kedgeA<<<512, 512, 0, stream>>>(hbf, rec, mW1, mb1, big, E);
  kedgeB<<<512, 512, 0, stream>>>(big, mW2, mb2, cW1, cb1, cW2, cb2, coef, E);
  kagg<<<(N + 15) / 16, 256, 0, stream>>>(big, rs, cnt32, coef, rec, x,
                                          mibf, (float*)d_out + (size_t)N * 128, N);
  int tb = ((N + 31) / 32 + 7) / 8;
  knode1<<<tb, 512, 0, stream>>>(hbf, mibf, hW1, hb1, big, N);
  knode2<<<tb, 512, 0, stream>>>(big, hW2, hb2, h, (float*)d_out, N);
}